// Round 1
// 2120.237 us; speedup vs baseline: 1.0545x; 1.0545x over previous
//
#include <hip/hip_runtime.h>
#include <hip/hip_bf16.h>
#include <cstdint>
#include <cstddef>

typedef unsigned short ushort_t;
typedef __attribute__((ext_vector_type(8))) __bf16 bf16x8;
typedef __attribute__((ext_vector_type(4))) float f32x4;
typedef __attribute__((ext_vector_type(4))) unsigned int u32x4;
typedef __attribute__((ext_vector_type(2))) unsigned int u32x2;

#define LOG2E 1.44269504088896f

__device__ __forceinline__ float bf2f(unsigned short u) {
  union { unsigned int i; float f; } w; w.i = ((unsigned int)u) << 16; return w.f;
}
__device__ __forceinline__ unsigned short f2bf(float f) {
  union { float f; unsigned int i; } w; w.f = f;
  unsigned int u = w.i;
  u += 0x7fffu + ((u >> 16) & 1);   // RNE
  return (unsigned short)(u >> 16);
}
__device__ __forceinline__ void gld_lds16(const void* g, void* l) {
  __builtin_amdgcn_global_load_lds(
      (const __attribute__((address_space(1))) unsigned int*)g,
      (__attribute__((address_space(3))) unsigned int*)l, 16, 0, 0);
}
// XOR-swizzle of a byte offset within a row: spreads stride-128B/256B row
// accesses across 8 distinct 16B bank slots (guide §6 G4, m214 +89%).
__device__ __forceinline__ int swz(int row, int byteoff) {
  return byteoff ^ ((row & 7) << 4);
}

// ---------------------------------------------------------------------------
// f32 -> bf16 weight conversion, 4 elems/thread.
// ---------------------------------------------------------------------------
__global__ __launch_bounds__(256)
void cvt_bf16(const float* __restrict__ in, ushort_t* __restrict__ outp, int n) {
  const int i = (blockIdx.x * 256 + threadIdx.x) * 4;
  if (i >= n) return;
  const float4 d = *(const float4*)(in + i);
  u32x2 o;
  o[0] = (unsigned int)f2bf(d.x) | ((unsigned int)f2bf(d.y) << 16);
  o[1] = (unsigned int)f2bf(d.z) | ((unsigned int)f2bf(d.w) << 16);
  *(u32x2*)(outp + i) = o;
}

// ---------------------------------------------------------------------------
// Generic bf16 GEMM: C[M,N] = A[M,K] @ B[N,K]^T, 128x128 tile, BK=64,
// 4 waves 2x2, each wave 64x64 via 4x4 MFMA 16x16x32 accs.
// EPI: 0 = plain bf16 store, 1 = f32 store Res + C*Scale[col], 2 = bf16 relu(C)^2
// ---------------------------------------------------------------------------
template <int EPI, typename OutT>
__global__ __launch_bounds__(256)
void gemm_bt(const ushort_t* __restrict__ A, const ushort_t* __restrict__ B,
             OutT* __restrict__ C, const float* __restrict__ Res,
             const float* __restrict__ Scale, int M, int N, int K) {
  __shared__ ushort_t As[128 * 64];
  __shared__ ushort_t Bs[128 * 64];
  const int tid = threadIdx.x;
  const int wave = tid >> 6, lane = tid & 63;
  const int quad = lane >> 4, l16 = lane & 15;
  const int bm = blockIdx.y * 128, bn = blockIdx.x * 128;
  const int wm = (wave >> 1) * 64, wn = (wave & 1) * 64;

  f32x4 acc[4][4] = {};

  const ushort_t* aBase = A + (size_t)bm * K;
  const ushort_t* bBase = B + (size_t)bn * K;
  for (int k0 = 0; k0 < K; k0 += 64) {
#pragma unroll
    for (int i = 0; i < 4; i++) {
      const int c = i * 256 + tid;
      const int r = c >> 3, cc = (c & 7) * 8;
      gld_lds16(aBase + (size_t)r * K + k0 + cc, &As[c * 8]);
      gld_lds16(bBase + (size_t)r * K + k0 + cc, &Bs[c * 8]);
    }
    __syncthreads();
#pragma unroll
    for (int ks = 0; ks < 2; ks++) {
      bf16x8 af[4], bfr[4];
#pragma unroll
      for (int t = 0; t < 4; t++) {
        af[t]  = *(const bf16x8*)&As[(wm + t * 16 + l16) * 64 + ks * 32 + quad * 8];
        bfr[t] = *(const bf16x8*)&Bs[(wn + t * 16 + l16) * 64 + ks * 32 + quad * 8];
      }
#pragma unroll
      for (int mt = 0; mt < 4; mt++)
#pragma unroll
        for (int nt = 0; nt < 4; nt++)
          acc[mt][nt] = __builtin_amdgcn_mfma_f32_16x16x32_bf16(af[mt], bfr[nt], acc[mt][nt], 0, 0, 0);
    }
    __syncthreads();
  }
  // epilogue: C/D layout col = lane&15, row = quad*4 + reg
#pragma unroll
  for (int mt = 0; mt < 4; mt++) {
#pragma unroll
    for (int r = 0; r < 4; r++) {
      const int row = bm + wm + mt * 16 + quad * 4 + r;
      const size_t base = (size_t)row * N;
#pragma unroll
      for (int nt = 0; nt < 4; nt++) {
        const int col = bn + wn + nt * 16 + l16;
        float v = acc[mt][nt][r];
        if (EPI == 1)      v = Res[base + col] + v * Scale[col];
        else if (EPI == 2) { v = fmaxf(v, 0.f); v = v * v; }
        if constexpr (sizeof(OutT) == 2) C[base + col] = f2bf(v);
        else                             C[base + col] = v;
      }
    }
  }
}

// ---------------------------------------------------------------------------
// Row RMSNorm over 2048 (f32 in, bf16 out), one block (256 thr) per row.
// ---------------------------------------------------------------------------
__global__ __launch_bounds__(256)
void rmsnorm_k(const float* __restrict__ X, ushort_t* __restrict__ Y) {
  const int row = blockIdx.x, tid = threadIdx.x;
  const float* x = X + (size_t)row * 2048 + tid * 8;
  float v[8];
  *(float4*)&v[0] = *(const float4*)x;
  *(float4*)&v[4] = *(const float4*)(x + 4);
  float ss = 0.f;
#pragma unroll
  for (int i = 0; i < 8; i++) ss += v[i] * v[i];
  for (int o = 32; o; o >>= 1) ss += __shfl_xor(ss, o, 64);
  __shared__ float red[4];
  if ((tid & 63) == 0) red[tid >> 6] = ss;
  __syncthreads();
  const float tot = red[0] + red[1] + red[2] + red[3];
  const float sc = rsqrtf(tot * (1.0f / 2048.0f) + 1e-6f);
  u32x4 o4;
#pragma unroll
  for (int i = 0; i < 4; i++)
    o4[i] = (unsigned int)f2bf(v[2 * i] * sc) | ((unsigned int)f2bf(v[2 * i + 1] * sc) << 16);
  *(u32x4*)(Y + (size_t)row * 2048 + tid * 8) = o4;
}

// ---------------------------------------------------------------------------
// QK-norm + rotary. One wave per (token, head). Lane l owns pair (l, l+64).
// q,k written back bf16 in-place into qkv buffer; k,v also written f32 to
// d_out sections.
// ---------------------------------------------------------------------------
__global__ __launch_bounds__(256)
void rotary_qk(ushort_t* __restrict__ qkv, float* __restrict__ kout,
               float* __restrict__ vout) {
  const int tid = threadIdx.x, wave = tid >> 6, lane = tid & 63;
  const int unit = blockIdx.x * 4 + wave;
  const int token = unit >> 4, h = unit & 15;
  const int t = token & 2047;
  ushort_t* qrow = qkv + (size_t)token * 6144 + h * 128;
  ushort_t* krow = qrow + 2048;
  const ushort_t* vrow = qrow + 4096;
  float q1 = bf2f(qrow[lane]), q2 = bf2f(qrow[lane + 64]);
  float k1 = bf2f(krow[lane]), k2 = bf2f(krow[lane + 64]);
  float sq = q1 * q1 + q2 * q2, sk = k1 * k1 + k2 * k2;
  for (int o = 32; o; o >>= 1) { sq += __shfl_xor(sq, o, 64); sk += __shfl_xor(sk, o, 64); }
  const float rq = rsqrtf(sq * (1.f / 128.f) + 1e-6f);
  const float rk = rsqrtf(sk * (1.f / 128.f) + 1e-6f);
  q1 *= rq; q2 *= rq; k1 *= rk; k2 *= rk;
  float c = 1.f, s = 0.f;
  if (lane < 32) {
    // f = 10000^(-lane/31); log2(10000)=13.28771237954945
    const float f = exp2f((float)lane * (-13.28771237954945f / 31.0f));
    const float th = (float)t * f;
    s = sinf(th); c = cosf(th);
  }
  const float qy1 = q1 * c + q2 * s, qy2 = -q1 * s + q2 * c;
  const float ky1 = k1 * c + k2 * s, ky2 = -k1 * s + k2 * c;
  const unsigned short qb1 = f2bf(qy1), qb2 = f2bf(qy2);
  const unsigned short kb1 = f2bf(ky1), kb2 = f2bf(ky2);
  qrow[lane] = qb1; qrow[lane + 64] = qb2;
  krow[lane] = kb1; krow[lane + 64] = kb2;
  float* ko = kout + (size_t)token * 2048 + h * 128;
  ko[lane] = bf2f(kb1); ko[lane + 64] = bf2f(kb2);
  float* vo = vout + (size_t)token * 2048 + h * 128;
  vo[lane] = bf2f(vrow[lane]); vo[lane + 64] = bf2f(vrow[lane + 64]);
}

// ---------------------------------------------------------------------------
// V transpose per (b,h): qkv v-section [T,128] -> Vt [128,T] (bf16) so flash
// PV B-operand reads are contiguous. 128x128 tile per block through padded LDS.
// ---------------------------------------------------------------------------
__global__ __launch_bounds__(256)
void transpose_v(const ushort_t* __restrict__ qkv, ushort_t* __restrict__ vt) {
  __shared__ ushort_t tile[128][136];
  const int t16 = blockIdx.x, h = blockIdx.y, b = blockIdx.z;
  const int tid = threadIdx.x;
#pragma unroll
  for (int i = 0; i < 8; i++) {
    const int c = i * 256 + tid;
    const int row = c >> 4, cc = (c & 15) * 8;
    const size_t tok = (size_t)(b * 2048 + t16 * 128 + row);
    u32x4 d = *(const u32x4*)(qkv + tok * 6144 + 4096 + h * 128 + cc);
    *(u32x4*)&tile[row][cc] = d;
  }
  __syncthreads();
#pragma unroll
  for (int i = 0; i < 8; i++) {
    const int c = i * 256 + tid;
    const int hr = c >> 4, tc = (c & 15) * 8;
    u32x4 o;
#pragma unroll
    for (int j = 0; j < 4; j++) {
      const unsigned int lo = tile[tc + 2 * j][hr];
      const unsigned int hi = tile[tc + 2 * j + 1][hr];
      o[j] = lo | (hi << 16);
    }
    *(u32x4*)(vt + ((size_t)(b * 16 + h) * 128 + hr) * 2048 + t16 * 128 + tc) = o;
  }
}

// ---------------------------------------------------------------------------
// Causal flash attention. Block = (qb,h,b): 128 q-rows, 4 waves x 32 rows.
// K-tile = 64 rows. Q frags in registers; K staged from qkv k-section
// [64][128]; V staged from pre-transposed Vt as [128 hd][64 k]; P through
// per-wave LDS (C->A layout).
//
// R1 changes:
//  - XOR bank swizzle (byte ^= (row&7)<<4) on kbuf/vbuf/pbuf. kbuf/vbuf are
//    filled by global_load_lds (linear dest), so the swizzle is applied by
//    permuting the 16B source chunk within each row (involution, coalescing
//    at 128B granularity preserved); reads apply the same XOR.
//  - Bijective block remap: XCD-chunked (same-(h,b) blocks share an XCD's L2
//    for the K/Vt panels) + qb issued descending (longest causal blocks
//    launch first -> short blocks fill the tail, fixing the 2..32-tile
//    imbalance behind OccupancyPercent=6.5%).
// ---------------------------------------------------------------------------
__global__ __launch_bounds__(256)
void attn_k(const ushort_t* __restrict__ qkv, const ushort_t* __restrict__ vt,
            ushort_t* __restrict__ obuf) {
  __shared__ ushort_t kbuf[64 * 128];
  __shared__ ushort_t vbuf[128 * 64];
  __shared__ ushort_t pbuf[4][32 * 64];
  // block remap: linear -> XCD-chunked, qb descending
  const int lin = blockIdx.x + (blockIdx.y << 4) + (blockIdx.z << 8);
  const int wid = ((lin & 7) << 7) + (lin >> 3);   // 1024 % 8 == 0 -> bijective
  const int qb = 15 - (wid & 15);
  const int h  = (wid >> 4) & 15;
  const int b  = wid >> 8;
  const int tid = threadIdx.x, wave = tid >> 6, lane = tid & 63;
  const int quad = lane >> 4, l16 = lane & 15;
  const float SCALE = 0.08838834764831845f;  // 1/sqrt(128)

  bf16x8 qf[2][4];
#pragma unroll
  for (int mt = 0; mt < 2; mt++)
#pragma unroll
    for (int ks = 0; ks < 4; ks++) {
      const int tok = b * 2048 + qb * 128 + wave * 32 + mt * 16 + l16;
      qf[mt][ks] = *(const bf16x8*)(qkv + (size_t)tok * 6144 + h * 128 + ks * 32 + quad * 8);
    }
  f32x4 O[2][8] = {};
  float mrow[2][4], lrow[2][4];
#pragma unroll
  for (int mt = 0; mt < 2; mt++)
#pragma unroll
    for (int r = 0; r < 4; r++) { mrow[mt][r] = -__builtin_inff(); lrow[mt][r] = 0.f; }

  const int nkt = qb * 2 + 2;
  const size_t kb0 = (size_t)(b * 2048) * 6144 + 2048 + h * 128;  // k-section row base
  const size_t vt0 = (size_t)(b * 16 + h) * 128 * 2048;
  for (int kt = 0; kt < nkt; kt++) {
#pragma unroll
    for (int i = 0; i < 4; i++) {
      const int c = i * 256 + tid;
      // kbuf: row kr (256B = 16 chunks); source chunk permuted by kr&7 so the
      // linear global_load_lds dest ends up XOR-swizzled.
      const int kr = c >> 4, ck = c & 15;
      gld_lds16(qkv + kb0 + (size_t)(kt * 64 + kr) * 6144 + (ck ^ (kr & 7)) * 8, &kbuf[c * 8]);
      // vbuf: row hr (128B = 8 chunks), same trick.
      const int hr = c >> 3, cv = c & 7;
      gld_lds16(vt + vt0 + (size_t)hr * 2048 + kt * 64 + (cv ^ (hr & 7)) * 8, &vbuf[c * 8]);
    }
    __syncthreads();
    f32x4 S[2][4] = {};
#pragma unroll
    for (int ks = 0; ks < 4; ks++) {
      bf16x8 kf[4];
#pragma unroll
      for (int nt = 0; nt < 4; nt++) {
        const int krow = nt * 16 + l16;
        kf[nt] = *(const bf16x8*)&kbuf[krow * 128 + (swz(krow, ks * 32 + quad * 8 << 1) >> 1)];
      }
#pragma unroll
      for (int mt = 0; mt < 2; mt++)
#pragma unroll
        for (int nt = 0; nt < 4; nt++)
          S[mt][nt] = __builtin_amdgcn_mfma_f32_16x16x32_bf16(qf[mt][ks], kf[nt], S[mt][nt], 0, 0, 0);
    }
    float alpha[2][4];
#pragma unroll
    for (int mt = 0; mt < 2; mt++) {
#pragma unroll
      for (int r = 0; r < 4; r++) {
        const int qr = qb * 128 + wave * 32 + mt * 16 + quad * 4 + r;
        float mx = -__builtin_inff();
#pragma unroll
        for (int nt = 0; nt < 4; nt++) {
          const int kc = kt * 64 + nt * 16 + l16;
          float sv = S[mt][nt][r] * SCALE;
          if (kc > qr) sv = -__builtin_inff();
          S[mt][nt][r] = sv;
          mx = fmaxf(mx, sv);
        }
        for (int o = 1; o < 16; o <<= 1) mx = fmaxf(mx, __shfl_xor(mx, o, 64));
        const float mnew = fmaxf(mrow[mt][r], mx);
        float rs = 0.f;
        const int prow = mt * 16 + quad * 4 + r;
#pragma unroll
        for (int nt = 0; nt < 4; nt++) {
          const float p = exp2f((S[mt][nt][r] - mnew) * LOG2E);
          rs += p;
          pbuf[wave][prow * 64 + (swz(prow, (nt * 16 + l16) * 2) >> 1)] = f2bf(p);
        }
        for (int o = 1; o < 16; o <<= 1) rs += __shfl_xor(rs, o, 64);
        const float a = exp2f((mrow[mt][r] - mnew) * LOG2E);
        alpha[mt][r] = a;
        lrow[mt][r] = lrow[mt][r] * a + rs;
        mrow[mt][r] = mnew;
      }
    }
#pragma unroll
    for (int mt = 0; mt < 2; mt++)
#pragma unroll
      for (int nto = 0; nto < 8; nto++)
#pragma unroll
        for (int r = 0; r < 4; r++)
          O[mt][nto][r] *= alpha[mt][r];
#pragma unroll
    for (int ks = 0; ks < 2; ks++) {
      bf16x8 pa[2];
#pragma unroll
      for (int mt = 0; mt < 2; mt++) {
        const int parow = mt * 16 + l16;
        pa[mt] = *(const bf16x8*)&pbuf[wave][parow * 64 + (swz(parow, ks * 64 + quad * 16) >> 1)];
      }
#pragma unroll
      for (int nto = 0; nto < 8; nto++) {
        const int vrow = nto * 16 + l16;
        const bf16x8 vb = *(const bf16x8*)&vbuf[vrow * 64 + (swz(vrow, ks * 64 + quad * 16) >> 1)];
#pragma unroll
        for (int mt = 0; mt < 2; mt++)
          O[mt][nto] = __builtin_amdgcn_mfma_f32_16x16x32_bf16(pa[mt], vb, O[mt][nto], 0, 0, 0);
      }
    }
    __syncthreads();
  }
#pragma unroll
  for (int mt = 0; mt < 2; mt++)
#pragma unroll
    for (int r = 0; r < 4; r++) {
      const float inv = 1.0f / lrow[mt][r];
      const int row = b * 2048 + qb * 128 + wave * 32 + mt * 16 + quad * 4 + r;
      const size_t base = (size_t)row * 2048 + h * 128;
#pragma unroll
      for (int nto = 0; nto < 8; nto++)
        obuf[base + nto * 16 + l16] = f2bf(O[mt][nto][r] * inv);
    }
}

// ---------------------------------------------------------------------------
extern "C" void kernel_launch(void* const* d_in, const int* in_sizes, int n_in,
                              void* d_out, int out_size, void* d_ws, size_t ws_size,
                              hipStream_t stream) {
  (void)in_sizes; (void)n_in; (void)out_size; (void)ws_size;
  const float* x       = (const float*)d_in[0];
  const float* qkv_w   = (const float*)d_in[1];
  const float* o_w     = (const float*)d_in[2];
  const float* o_scale = (const float*)d_in[3];
  const float* w1      = (const float*)d_in[4];
  const float* w2      = (const float*)d_in[5];
  const float* mscale  = (const float*)d_in[6];
  float* outx = (float*)d_out;                       // [4,2048,2048]   = 16777216
  float* outk = outx + (size_t)16777216;             // [4,2048,16,128] = 16777216
  float* outv = outk + (size_t)16777216;             // [4,2048,16,128] = 16777216

  char* ws = (char*)d_ws;
  ushort_t* qkv    = (ushort_t*)(ws + 0);            // 96 MB  [8192,6144] bf16
  ushort_t* vt     = (ushort_t*)(ws + 100663296);    // 32 MB  [4,16,128,2048] bf16
  ushort_t* xn     = (ushort_t*)(ws + 134217728);    // 32 MB  bf16 (xn / o / xn2 serial reuse)
  float*    x1     = (float*)   (ws + 167772160);    // 64 MB  f32
  ushort_t* qkv_wb = (ushort_t*)(ws + 234881024);    // 24 MB  bf16
  ushort_t* o_wb   = (ushort_t*)(ws + 260046848);    //  8 MB
  ushort_t* w1b    = (ushort_t*)(ws + 268435456);    // 32 MB
  ushort_t* w2b    = (ushort_t*)(ws + 301989888);    // 32 MB  (total 320 MB)
  ushort_t* hbuf   = (ushort_t*)(ws + 0);            // 128 MB overlays qkv+vt (dead after attn)

  cvt_bf16<<<12288, 256, 0, stream>>>(qkv_w, qkv_wb, 12582912);
  cvt_bf16<<<4096,  256, 0, stream>>>(o_w,   o_wb,   4194304);
  cvt_bf16<<<16384, 256, 0, stream>>>(w1,    w1b,    16777216);
  cvt_bf16<<<16384, 256, 0, stream>>>(w2,    w2b,    16777216);

  rmsnorm_k<<<8192, 256, 0, stream>>>(x, xn);
  gemm_bt<0, ushort_t><<<dim3(48, 64), 256, 0, stream>>>(xn, qkv_wb, qkv, nullptr, nullptr, 8192, 6144, 2048);
  rotary_qk<<<32768, 256, 0, stream>>>(qkv, outk, outv);
  transpose_v<<<dim3(16, 16, 4), 256, 0, stream>>>(qkv, vt);
  attn_k<<<dim3(16, 16, 4), 256, 0, stream>>>(qkv, vt, xn /* o */);
  gemm_bt<1, float><<<dim3(16, 64), 256, 0, stream>>>(xn /* o */, o_wb, x1, x, o_scale, 8192, 2048, 2048);
  rmsnorm_k<<<8192, 256, 0, stream>>>(x1, xn);
  gemm_bt<2, ushort_t><<<dim3(64, 64), 256, 0, stream>>>(xn, w1b, hbuf, nullptr, nullptr, 8192, 8192, 2048);
  gemm_bt<1, float><<<dim3(16, 64), 256, 0, stream>>>(hbuf, w2b, outx, x1, mscale, 8192, 2048, 8192);
}

// Round 2
// 1761.366 us; speedup vs baseline: 1.2693x; 1.2037x over previous
//
#include <hip/hip_runtime.h>
#include <hip/hip_bf16.h>
#include <cstdint>
#include <cstddef>

typedef unsigned short ushort_t;
typedef __attribute__((ext_vector_type(8))) __bf16 bf16x8;
typedef __attribute__((ext_vector_type(4))) float f32x4;
typedef __attribute__((ext_vector_type(4))) unsigned int u32x4;
typedef __attribute__((ext_vector_type(2))) unsigned int u32x2;

#define LOG2E 1.44269504088896f

__device__ __forceinline__ float bf2f(unsigned short u) {
  union { unsigned int i; float f; } w; w.i = ((unsigned int)u) << 16; return w.f;
}
__device__ __forceinline__ unsigned short f2bf(float f) {
  union { float f; unsigned int i; } w; w.f = f;
  unsigned int u = w.i;
  u += 0x7fffu + ((u >> 16) & 1);   // RNE
  return (unsigned short)(u >> 16);
}
__device__ __forceinline__ void gld_lds16(const void* g, void* l) {
  __builtin_amdgcn_global_load_lds(
      (const __attribute__((address_space(1))) unsigned int*)g,
      (__attribute__((address_space(3))) unsigned int*)l, 16, 0, 0);
}
// XOR-swizzle of a byte offset within a row (rows of 128B/256B): spreads the
// quad's 16-row column reads across 8 distinct 16B bank slots.
__device__ __forceinline__ int swz(int row, int byteoff) {
  return byteoff ^ ((row & 7) << 4);
}

// ---------------------------------------------------------------------------
// f32 -> bf16 weight conversion, 4 elems/thread.
// ---------------------------------------------------------------------------
__global__ __launch_bounds__(256)
void cvt_bf16(const float* __restrict__ in, ushort_t* __restrict__ outp, int n) {
  const int i = (blockIdx.x * 256 + threadIdx.x) * 4;
  if (i >= n) return;
  const float4 d = *(const float4*)(in + i);
  u32x2 o;
  o[0] = (unsigned int)f2bf(d.x) | ((unsigned int)f2bf(d.y) << 16);
  o[1] = (unsigned int)f2bf(d.z) | ((unsigned int)f2bf(d.w) << 16);
  *(u32x2*)(outp + i) = o;
}

// ---------------------------------------------------------------------------
// Phased 256x256 bf16 GEMM: C[M,N] = A[M,K] @ B[N,K]^T.
// BK=64, 512 threads = 8 waves (2M x 4N), per-wave 128x64 output
// (acc[8][4] of 16x16 frags). Double-buffered LDS (2 x (A 32KB + B 32KB)).
// Per K-tile: 4 phases, each = {ds-read quadrant frags | stage 1 half-tile
// prefetch of tile t+1 -> barrier -> setprio(1) 16 MFMA setprio(0) ->
// barrier}; single vmcnt(0) per K-tile at phase 3 (loads were issued 1-4
// phases earlier -> latency hidden under compute, unlike the old
// issue+drain-per-tile loop).  T2 XOR swizzle both-sides (pre-swizzled
// global source chunk + swizzled ds_read).  T1 XCD-bijective remap.
// EPI: 0 = bf16 store, 1 = f32 store Res + C*Scale[col], 2 = bf16 relu(C)^2
// ---------------------------------------------------------------------------
__device__ __forceinline__ void stage_half(const ushort_t* __restrict__ gsrc,
                                           size_t rstride, ushort_t* ldst, int tid) {
#pragma unroll
  for (int i = 0; i < 2; i++) {
    const int c = i * 512 + tid;
    const int r = c >> 3, col = c & 7;
    // linear LDS dest chunk (c&7) <- global chunk ((c&7) ^ (r&7))  [involution]
    gld_lds16(gsrc + (size_t)r * rstride + ((col ^ (r & 7)) << 3), ldst + c * 8);
  }
}

template <int EPI, typename OutT>
__global__ __launch_bounds__(512, 2)
void gemm_bt256(const ushort_t* __restrict__ A, const ushort_t* __restrict__ B,
                OutT* __restrict__ C, const float* __restrict__ Res,
                const float* __restrict__ Scale, int M, int N, int K) {
  __shared__ ushort_t As[2][256 * 64];
  __shared__ ushort_t Bs[2][256 * 64];
  const int tid = threadIdx.x;
  const int wave = tid >> 6, lane = tid & 63;
  const int quad = lane >> 4, l16 = lane & 15;
  // T1: bijective XCD remap (all grids here have nwg % 8 == 0), N-major so
  // consecutive wids within an XCD chunk share the A panel (L2-resident).
  const int ntn = N >> 8;
  const int nwg = (M >> 8) * ntn;
  const int lin = blockIdx.y * gridDim.x + blockIdx.x;
  const int wid = (lin & 7) * (nwg >> 3) + (lin >> 3);
  const int bn = (wid % ntn) << 8;
  const int bm = (wid / ntn) << 8;
  const int wm = (wave >> 2) * 128, wn = (wave & 3) * 64;

  f32x4 acc[8][4] = {};

  const ushort_t* aB = A + (size_t)bm * K;
  const ushort_t* bB = B + (size_t)bn * K;
  const int nk = K >> 6;

  // prologue: stage tile 0 into buf 0, full drain.
  stage_half(aB, K, &As[0][0], tid);
  stage_half(aB + (size_t)128 * K, K, &As[0][8192], tid);
  stage_half(bB, K, &Bs[0][0], tid);
  stage_half(bB + (size_t)128 * K, K, &Bs[0][8192], tid);
  asm volatile("s_waitcnt vmcnt(0)" ::: "memory");
  __builtin_amdgcn_sched_barrier(0);
  __builtin_amdgcn_s_barrier();

  for (int t = 0; t < nk; ++t) {
    const int cur = t & 1, nb = cur ^ 1;
    const ushort_t* Ac = &As[cur][0];
    const ushort_t* Bc = &Bs[cur][0];
    const int k0n = (t + 1) << 6;
    const bool pf = (t + 1 < nk);
#pragma unroll
    for (int q = 0; q < 4; q++) {
      const int mh = q >> 1, nh = q & 1;
      bf16x8 af[4][2], bfq[2][2];
#pragma unroll
      for (int j = 0; j < 4; j++) {
        const int row = wm + (mh * 4 + j) * 16 + l16;
#pragma unroll
        for (int ks = 0; ks < 2; ks++)
          af[j][ks] = *(const bf16x8*)&Ac[row * 64 + (swz(row, ks * 64 + quad * 16) >> 1)];
      }
#pragma unroll
      for (int j = 0; j < 2; j++) {
        const int row = wn + (nh * 2 + j) * 16 + l16;
#pragma unroll
        for (int ks = 0; ks < 2; ks++)
          bfq[j][ks] = *(const bf16x8*)&Bc[row * 64 + (swz(row, ks * 64 + quad * 16) >> 1)];
      }
      // stage one half-tile of tile t+1 into the other buffer (never read
      // this iteration -> race-free; drained at q==3 before next iteration).
      if (pf) {
        if (q == 0)      stage_half(aB + k0n, K, &As[nb][0], tid);
        else if (q == 1) stage_half(aB + (size_t)128 * K + k0n, K, &As[nb][8192], tid);
        else if (q == 2) {
          stage_half(bB + k0n, K, &Bs[nb][0], tid);
          stage_half(bB + (size_t)128 * K + k0n, K, &Bs[nb][8192], tid);
        }
      }
      __builtin_amdgcn_sched_barrier(0);
      __builtin_amdgcn_s_barrier();
      __builtin_amdgcn_s_setprio(1);
#pragma unroll
      for (int j = 0; j < 4; j++)
#pragma unroll
        for (int n2 = 0; n2 < 2; n2++)
#pragma unroll
          for (int ks = 0; ks < 2; ks++)
            acc[mh * 4 + j][nh * 2 + n2] = __builtin_amdgcn_mfma_f32_16x16x32_bf16(
                af[j][ks], bfq[n2][ks], acc[mh * 4 + j][nh * 2 + n2], 0, 0, 0);
      __builtin_amdgcn_s_setprio(0);
      if (q == 3) {
        // single counted drain per K-tile: the 8 stage loads were issued
        // 1-4 phases ago; memory clobber also fences IR-level load motion
        // across the iteration boundary.
        asm volatile("s_waitcnt vmcnt(0)" ::: "memory");
      }
      __builtin_amdgcn_sched_barrier(0);
      __builtin_amdgcn_s_barrier();
    }
  }

  // epilogue: C/D layout col = lane&15, row = quad*4 + reg
#pragma unroll
  for (int mt = 0; mt < 8; mt++) {
#pragma unroll
    for (int r = 0; r < 4; r++) {
      const int row = bm + wm + mt * 16 + quad * 4 + r;
      const size_t base = (size_t)row * N;
#pragma unroll
      for (int nt = 0; nt < 4; nt++) {
        const int col = bn + wn + nt * 16 + l16;
        float v = acc[mt][nt][r];
        if (EPI == 1)      v = Res[base + col] + v * Scale[col];
        else if (EPI == 2) { v = fmaxf(v, 0.f); v = v * v; }
        if constexpr (sizeof(OutT) == 2) C[base + col] = f2bf(v);
        else                             C[base + col] = v;
      }
    }
  }
}

// ---------------------------------------------------------------------------
// Row RMSNorm over 2048 (f32 in, bf16 out), one block (256 thr) per row.
// ---------------------------------------------------------------------------
__global__ __launch_bounds__(256)
void rmsnorm_k(const float* __restrict__ X, ushort_t* __restrict__ Y) {
  const int row = blockIdx.x, tid = threadIdx.x;
  const float* x = X + (size_t)row * 2048 + tid * 8;
  float v[8];
  *(float4*)&v[0] = *(const float4*)x;
  *(float4*)&v[4] = *(const float4*)(x + 4);
  float ss = 0.f;
#pragma unroll
  for (int i = 0; i < 8; i++) ss += v[i] * v[i];
  for (int o = 32; o; o >>= 1) ss += __shfl_xor(ss, o, 64);
  __shared__ float red[4];
  if ((tid & 63) == 0) red[tid >> 6] = ss;
  __syncthreads();
  const float tot = red[0] + red[1] + red[2] + red[3];
  const float sc = rsqrtf(tot * (1.0f / 2048.0f) + 1e-6f);
  u32x4 o4;
#pragma unroll
  for (int i = 0; i < 4; i++)
    o4[i] = (unsigned int)f2bf(v[2 * i] * sc) | ((unsigned int)f2bf(v[2 * i + 1] * sc) << 16);
  *(u32x4*)(Y + (size_t)row * 2048 + tid * 8) = o4;
}

// ---------------------------------------------------------------------------
// QK-norm + rotary. One wave per (token, head). Lane l owns pair (l, l+64).
// ---------------------------------------------------------------------------
__global__ __launch_bounds__(256)
void rotary_qk(ushort_t* __restrict__ qkv, float* __restrict__ kout,
               float* __restrict__ vout) {
  const int tid = threadIdx.x, wave = tid >> 6, lane = tid & 63;
  const int unit = blockIdx.x * 4 + wave;
  const int token = unit >> 4, h = unit & 15;
  const int t = token & 2047;
  ushort_t* qrow = qkv + (size_t)token * 6144 + h * 128;
  ushort_t* krow = qrow + 2048;
  const ushort_t* vrow = qrow + 4096;
  float q1 = bf2f(qrow[lane]), q2 = bf2f(qrow[lane + 64]);
  float k1 = bf2f(krow[lane]), k2 = bf2f(krow[lane + 64]);
  float sq = q1 * q1 + q2 * q2, sk = k1 * k1 + k2 * k2;
  for (int o = 32; o; o >>= 1) { sq += __shfl_xor(sq, o, 64); sk += __shfl_xor(sk, o, 64); }
  const float rq = rsqrtf(sq * (1.f / 128.f) + 1e-6f);
  const float rk = rsqrtf(sk * (1.f / 128.f) + 1e-6f);
  q1 *= rq; q2 *= rq; k1 *= rk; k2 *= rk;
  float c = 1.f, s = 0.f;
  if (lane < 32) {
    const float f = exp2f((float)lane * (-13.28771237954945f / 31.0f));
    const float th = (float)t * f;
    s = sinf(th); c = cosf(th);
  }
  const float qy1 = q1 * c + q2 * s, qy2 = -q1 * s + q2 * c;
  const float ky1 = k1 * c + k2 * s, ky2 = -k1 * s + k2 * c;
  const unsigned short qb1 = f2bf(qy1), qb2 = f2bf(qy2);
  const unsigned short kb1 = f2bf(ky1), kb2 = f2bf(ky2);
  qrow[lane] = qb1; qrow[lane + 64] = qb2;
  krow[lane] = kb1; krow[lane + 64] = kb2;
  float* ko = kout + (size_t)token * 2048 + h * 128;
  ko[lane] = bf2f(kb1); ko[lane + 64] = bf2f(kb2);
  float* vo = vout + (size_t)token * 2048 + h * 128;
  vo[lane] = bf2f(vrow[lane]); vo[lane + 64] = bf2f(vrow[lane + 64]);
}

// ---------------------------------------------------------------------------
// V transpose per (b,h): qkv v-section [T,128] -> Vt [128,T] (bf16).
// ---------------------------------------------------------------------------
__global__ __launch_bounds__(256)
void transpose_v(const ushort_t* __restrict__ qkv, ushort_t* __restrict__ vt) {
  __shared__ ushort_t tile[128][136];
  const int t16 = blockIdx.x, h = blockIdx.y, b = blockIdx.z;
  const int tid = threadIdx.x;
#pragma unroll
  for (int i = 0; i < 8; i++) {
    const int c = i * 256 + tid;
    const int row = c >> 4, cc = (c & 15) * 8;
    const size_t tok = (size_t)(b * 2048 + t16 * 128 + row);
    u32x4 d = *(const u32x4*)(qkv + tok * 6144 + 4096 + h * 128 + cc);
    *(u32x4*)&tile[row][cc] = d;
  }
  __syncthreads();
#pragma unroll
  for (int i = 0; i < 8; i++) {
    const int c = i * 256 + tid;
    const int hr = c >> 4, tc = (c & 15) * 8;
    u32x4 o;
#pragma unroll
    for (int j = 0; j < 4; j++) {
      const unsigned int lo = tile[tc + 2 * j][hr];
      const unsigned int hi = tile[tc + 2 * j + 1][hr];
      o[j] = lo | (hi << 16);
    }
    *(u32x4*)(vt + ((size_t)(b * 16 + h) * 128 + hr) * 2048 + t16 * 128 + tc) = o;
  }
}

// ---------------------------------------------------------------------------
// Causal flash attention (R1 structure: swizzled kbuf/vbuf/pbuf, XCD-chunked
// remap with qb descending). Unchanged this round.
// ---------------------------------------------------------------------------
__global__ __launch_bounds__(256)
void attn_k(const ushort_t* __restrict__ qkv, const ushort_t* __restrict__ vt,
            ushort_t* __restrict__ obuf) {
  __shared__ ushort_t kbuf[64 * 128];
  __shared__ ushort_t vbuf[128 * 64];
  __shared__ ushort_t pbuf[4][32 * 64];
  const int lin = blockIdx.x + (blockIdx.y << 4) + (blockIdx.z << 8);
  const int wid = ((lin & 7) << 7) + (lin >> 3);   // 1024 % 8 == 0 -> bijective
  const int qb = 15 - (wid & 15);
  const int h  = (wid >> 4) & 15;
  const int b  = wid >> 8;
  const int tid = threadIdx.x, wave = tid >> 6, lane = tid & 63;
  const int quad = lane >> 4, l16 = lane & 15;
  const float SCALE = 0.08838834764831845f;  // 1/sqrt(128)

  bf16x8 qf[2][4];
#pragma unroll
  for (int mt = 0; mt < 2; mt++)
#pragma unroll
    for (int ks = 0; ks < 4; ks++) {
      const int tok = b * 2048 + qb * 128 + wave * 32 + mt * 16 + l16;
      qf[mt][ks] = *(const bf16x8*)(qkv + (size_t)tok * 6144 + h * 128 + ks * 32 + quad * 8);
    }
  f32x4 O[2][8] = {};
  float mrow[2][4], lrow[2][4];
#pragma unroll
  for (int mt = 0; mt < 2; mt++)
#pragma unroll
    for (int r = 0; r < 4; r++) { mrow[mt][r] = -__builtin_inff(); lrow[mt][r] = 0.f; }

  const int nkt = qb * 2 + 2;
  const size_t kb0 = (size_t)(b * 2048) * 6144 + 2048 + h * 128;
  const size_t vt0 = (size_t)(b * 16 + h) * 128 * 2048;
  for (int kt = 0; kt < nkt; kt++) {
#pragma unroll
    for (int i = 0; i < 4; i++) {
      const int c = i * 256 + tid;
      const int kr = c >> 4, ck = c & 15;
      gld_lds16(qkv + kb0 + (size_t)(kt * 64 + kr) * 6144 + (ck ^ (kr & 7)) * 8, &kbuf[c * 8]);
      const int hr = c >> 3, cv = c & 7;
      gld_lds16(vt + vt0 + (size_t)hr * 2048 + kt * 64 + (cv ^ (hr & 7)) * 8, &vbuf[c * 8]);
    }
    __syncthreads();
    f32x4 S[2][4] = {};
#pragma unroll
    for (int ks = 0; ks < 4; ks++) {
      bf16x8 kf[4];
#pragma unroll
      for (int nt = 0; nt < 4; nt++) {
        const int krow = nt * 16 + l16;
        kf[nt] = *(const bf16x8*)&kbuf[krow * 128 + (swz(krow, ks * 64 + quad * 16) >> 1)];
      }
#pragma unroll
      for (int mt = 0; mt < 2; mt++)
#pragma unroll
        for (int nt = 0; nt < 4; nt++)
          S[mt][nt] = __builtin_amdgcn_mfma_f32_16x16x32_bf16(qf[mt][ks], kf[nt], S[mt][nt], 0, 0, 0);
    }
    float alpha[2][4];
#pragma unroll
    for (int mt = 0; mt < 2; mt++) {
#pragma unroll
      for (int r = 0; r < 4; r++) {
        const int qr = qb * 128 + wave * 32 + mt * 16 + quad * 4 + r;
        float mx = -__builtin_inff();
#pragma unroll
        for (int nt = 0; nt < 4; nt++) {
          const int kc = kt * 64 + nt * 16 + l16;
          float sv = S[mt][nt][r] * SCALE;
          if (kc > qr) sv = -__builtin_inff();
          S[mt][nt][r] = sv;
          mx = fmaxf(mx, sv);
        }
        for (int o = 1; o < 16; o <<= 1) mx = fmaxf(mx, __shfl_xor(mx, o, 64));
        const float mnew = fmaxf(mrow[mt][r], mx);
        float rs = 0.f;
        const int prow = mt * 16 + quad * 4 + r;
#pragma unroll
        for (int nt = 0; nt < 4; nt++) {
          const float p = exp2f((S[mt][nt][r] - mnew) * LOG2E);
          rs += p;
          pbuf[wave][prow * 64 + (swz(prow, (nt * 16 + l16) * 2) >> 1)] = f2bf(p);
        }
        for (int o = 1; o < 16; o <<= 1) rs += __shfl_xor(rs, o, 64);
        const float a = exp2f((mrow[mt][r] - mnew) * LOG2E);
        alpha[mt][r] = a;
        lrow[mt][r] = lrow[mt][r] * a + rs;
        mrow[mt][r] = mnew;
      }
    }
#pragma unroll
    for (int mt = 0; mt < 2; mt++)
#pragma unroll
      for (int nto = 0; nto < 8; nto++)
#pragma unroll
        for (int r = 0; r < 4; r++)
          O[mt][nto][r] *= alpha[mt][r];
#pragma unroll
    for (int ks = 0; ks < 2; ks++) {
      bf16x8 pa[2];
#pragma unroll
      for (int mt = 0; mt < 2; mt++) {
        const int parow = mt * 16 + l16;
        pa[mt] = *(const bf16x8*)&pbuf[wave][parow * 64 + (swz(parow, ks * 64 + quad * 16) >> 1)];
      }
#pragma unroll
      for (int nto = 0; nto < 8; nto++) {
        const int vrow = nto * 16 + l16;
        const bf16x8 vb = *(const bf16x8*)&vbuf[vrow * 64 + (swz(vrow, ks * 64 + quad * 16) >> 1)];
#pragma unroll
        for (int mt = 0; mt < 2; mt++)
          O[mt][nto] = __builtin_amdgcn_mfma_f32_16x16x32_bf16(pa[mt], vb, O[mt][nto], 0, 0, 0);
      }
    }
    __syncthreads();
  }
#pragma unroll
  for (int mt = 0; mt < 2; mt++)
#pragma unroll
    for (int r = 0; r < 4; r++) {
      const float inv = 1.0f / lrow[mt][r];
      const int row = b * 2048 + qb * 128 + wave * 32 + mt * 16 + quad * 4 + r;
      const size_t base = (size_t)row * 2048 + h * 128;
#pragma unroll
      for (int nto = 0; nto < 8; nto++)
        obuf[base + nto * 16 + l16] = f2bf(O[mt][nto][r] * inv);
    }
}

// ---------------------------------------------------------------------------
extern "C" void kernel_launch(void* const* d_in, const int* in_sizes, int n_in,
                              void* d_out, int out_size, void* d_ws, size_t ws_size,
                              hipStream_t stream) {
  (void)in_sizes; (void)n_in; (void)out_size; (void)ws_size;
  const float* x       = (const float*)d_in[0];
  const float* qkv_w   = (const float*)d_in[1];
  const float* o_w     = (const float*)d_in[2];
  const float* o_scale = (const float*)d_in[3];
  const float* w1      = (const float*)d_in[4];
  const float* w2      = (const float*)d_in[5];
  const float* mscale  = (const float*)d_in[6];
  float* outx = (float*)d_out;                       // [4,2048,2048]   = 16777216
  float* outk = outx + (size_t)16777216;             // [4,2048,16,128] = 16777216
  float* outv = outk + (size_t)16777216;             // [4,2048,16,128] = 16777216

  char* ws = (char*)d_ws;
  ushort_t* qkv    = (ushort_t*)(ws + 0);            // 96 MB  [8192,6144] bf16
  ushort_t* vt     = (ushort_t*)(ws + 100663296);    // 32 MB  [4,16,128,2048] bf16
  ushort_t* xn     = (ushort_t*)(ws + 134217728);    // 32 MB  bf16 (xn / o / xn2 serial reuse)
  float*    x1     = (float*)   (ws + 167772160);    // 64 MB  f32
  ushort_t* qkv_wb = (ushort_t*)(ws + 234881024);    // 24 MB  bf16
  ushort_t* o_wb   = (ushort_t*)(ws + 260046848);    //  8 MB
  ushort_t* w1b    = (ushort_t*)(ws + 268435456);    // 32 MB
  ushort_t* w2b    = (ushort_t*)(ws + 301989888);    // 32 MB  (total 320 MB)
  ushort_t* hbuf   = (ushort_t*)(ws + 0);            // 128 MB overlays qkv+vt (dead after attn)

  cvt_bf16<<<12288, 256, 0, stream>>>(qkv_w, qkv_wb, 12582912);
  cvt_bf16<<<4096,  256, 0, stream>>>(o_w,   o_wb,   4194304);
  cvt_bf16<<<16384, 256, 0, stream>>>(w1,    w1b,    16777216);
  cvt_bf16<<<16384, 256, 0, stream>>>(w2,    w2b,    16777216);

  rmsnorm_k<<<8192, 256, 0, stream>>>(x, xn);
  gemm_bt256<0, ushort_t><<<dim3(24, 32), 512, 0, stream>>>(xn, qkv_wb, qkv, nullptr, nullptr, 8192, 6144, 2048);
  rotary_qk<<<32768, 256, 0, stream>>>(qkv, outk, outv);
  transpose_v<<<dim3(16, 16, 4), 256, 0, stream>>>(qkv, vt);
  attn_k<<<dim3(16, 16, 4), 256, 0, stream>>>(qkv, vt, xn /* o */);
  gemm_bt256<1, float><<<dim3(8, 32), 512, 0, stream>>>(xn /* o */, o_wb, x1, x, o_scale, 8192, 2048, 2048);
  rmsnorm_k<<<8192, 256, 0, stream>>>(x1, xn);
  gemm_bt256<2, ushort_t><<<dim3(32, 32), 512, 0, stream>>>(xn, w1b, hbuf, nullptr, nullptr, 8192, 8192, 2048);
  gemm_bt256<1, float><<<dim3(8, 32), 512, 0, stream>>>(hbuf, w2b, outx, x1, mscale, 8192, 2048, 8192);
}

// Round 3
// 1753.082 us; speedup vs baseline: 1.2753x; 1.0047x over previous
//
#include <hip/hip_runtime.h>
#include <hip/hip_bf16.h>
#include <cstdint>
#include <cstddef>

typedef unsigned short ushort_t;
typedef __attribute__((ext_vector_type(8))) __bf16 bf16x8;
typedef __attribute__((ext_vector_type(4))) float f32x4;
typedef __attribute__((ext_vector_type(4))) unsigned int u32x4;
typedef __attribute__((ext_vector_type(2))) unsigned int u32x2;

#define LOG2E 1.44269504088896f

__device__ __forceinline__ float bf2f(unsigned short u) {
  union { unsigned int i; float f; } w; w.i = ((unsigned int)u) << 16; return w.f;
}
__device__ __forceinline__ unsigned short f2bf(float f) {
  union { float f; unsigned int i; } w; w.f = f;
  unsigned int u = w.i;
  u += 0x7fffu + ((u >> 16) & 1);   // RNE
  return (unsigned short)(u >> 16);
}
__device__ __forceinline__ void gld_lds16(const void* g, void* l) {
  __builtin_amdgcn_global_load_lds(
      (const __attribute__((address_space(1))) unsigned int*)g,
      (__attribute__((address_space(3))) unsigned int*)l, 16, 0, 0);
}
// XOR-swizzle of a byte offset within a row (rows of 128B/256B): spreads the
// quad's 16-row column reads across 8 distinct 16B bank slots.
__device__ __forceinline__ int swz(int row, int byteoff) {
  return byteoff ^ ((row & 7) << 4);
}

// ---------------------------------------------------------------------------
// f32 -> bf16 weight conversion, 4 elems/thread.
// ---------------------------------------------------------------------------
__global__ __launch_bounds__(256)
void cvt_bf16(const float* __restrict__ in, ushort_t* __restrict__ outp, int n) {
  const int i = (blockIdx.x * 256 + threadIdx.x) * 4;
  if (i >= n) return;
  const float4 d = *(const float4*)(in + i);
  u32x2 o;
  o[0] = (unsigned int)f2bf(d.x) | ((unsigned int)f2bf(d.y) << 16);
  o[1] = (unsigned int)f2bf(d.z) | ((unsigned int)f2bf(d.w) << 16);
  *(u32x2*)(outp + i) = o;
}

// ---------------------------------------------------------------------------
// Phased 256x256 bf16 GEMM (R2 structure, unchanged): BK=64, 8 waves (2Mx4N),
// double-buffered LDS, 4 phases/K-tile, single vmcnt(0)/tile, T2 swizzle
// both-sides, T1 XCD remap, T5 setprio.
// ---------------------------------------------------------------------------
__device__ __forceinline__ void stage_half(const ushort_t* __restrict__ gsrc,
                                           size_t rstride, ushort_t* ldst, int tid) {
#pragma unroll
  for (int i = 0; i < 2; i++) {
    const int c = i * 512 + tid;
    const int r = c >> 3, col = c & 7;
    gld_lds16(gsrc + (size_t)r * rstride + ((col ^ (r & 7)) << 3), ldst + c * 8);
  }
}

template <int EPI, typename OutT>
__global__ __launch_bounds__(512, 2)
void gemm_bt256(const ushort_t* __restrict__ A, const ushort_t* __restrict__ B,
                OutT* __restrict__ C, const float* __restrict__ Res,
                const float* __restrict__ Scale, int M, int N, int K) {
  __shared__ ushort_t As[2][256 * 64];
  __shared__ ushort_t Bs[2][256 * 64];
  const int tid = threadIdx.x;
  const int wave = tid >> 6, lane = tid & 63;
  const int quad = lane >> 4, l16 = lane & 15;
  const int ntn = N >> 8;
  const int nwg = (M >> 8) * ntn;
  const int lin = blockIdx.y * gridDim.x + blockIdx.x;
  const int wid = (lin & 7) * (nwg >> 3) + (lin >> 3);
  const int bn = (wid % ntn) << 8;
  const int bm = (wid / ntn) << 8;
  const int wm = (wave >> 2) * 128, wn = (wave & 3) * 64;

  f32x4 acc[8][4] = {};

  const ushort_t* aB = A + (size_t)bm * K;
  const ushort_t* bB = B + (size_t)bn * K;
  const int nk = K >> 6;

  stage_half(aB, K, &As[0][0], tid);
  stage_half(aB + (size_t)128 * K, K, &As[0][8192], tid);
  stage_half(bB, K, &Bs[0][0], tid);
  stage_half(bB + (size_t)128 * K, K, &Bs[0][8192], tid);
  asm volatile("s_waitcnt vmcnt(0)" ::: "memory");
  __builtin_amdgcn_sched_barrier(0);
  __builtin_amdgcn_s_barrier();

  for (int t = 0; t < nk; ++t) {
    const int cur = t & 1, nb = cur ^ 1;
    const ushort_t* Ac = &As[cur][0];
    const ushort_t* Bc = &Bs[cur][0];
    const int k0n = (t + 1) << 6;
    const bool pf = (t + 1 < nk);
#pragma unroll
    for (int q = 0; q < 4; q++) {
      const int mh = q >> 1, nh = q & 1;
      bf16x8 af[4][2], bfq[2][2];
#pragma unroll
      for (int j = 0; j < 4; j++) {
        const int row = wm + (mh * 4 + j) * 16 + l16;
#pragma unroll
        for (int ks = 0; ks < 2; ks++)
          af[j][ks] = *(const bf16x8*)&Ac[row * 64 + (swz(row, ks * 64 + quad * 16) >> 1)];
      }
#pragma unroll
      for (int j = 0; j < 2; j++) {
        const int row = wn + (nh * 2 + j) * 16 + l16;
#pragma unroll
        for (int ks = 0; ks < 2; ks++)
          bfq[j][ks] = *(const bf16x8*)&Bc[row * 64 + (swz(row, ks * 64 + quad * 16) >> 1)];
      }
      if (pf) {
        if (q == 0)      stage_half(aB + k0n, K, &As[nb][0], tid);
        else if (q == 1) stage_half(aB + (size_t)128 * K + k0n, K, &As[nb][8192], tid);
        else if (q == 2) {
          stage_half(bB + k0n, K, &Bs[nb][0], tid);
          stage_half(bB + (size_t)128 * K + k0n, K, &Bs[nb][8192], tid);
        }
      }
      __builtin_amdgcn_sched_barrier(0);
      __builtin_amdgcn_s_barrier();
      __builtin_amdgcn_s_setprio(1);
#pragma unroll
      for (int j = 0; j < 4; j++)
#pragma unroll
        for (int n2 = 0; n2 < 2; n2++)
#pragma unroll
          for (int ks = 0; ks < 2; ks++)
            acc[mh * 4 + j][nh * 2 + n2] = __builtin_amdgcn_mfma_f32_16x16x32_bf16(
                af[j][ks], bfq[n2][ks], acc[mh * 4 + j][nh * 2 + n2], 0, 0, 0);
      __builtin_amdgcn_s_setprio(0);
      if (q == 3) {
        asm volatile("s_waitcnt vmcnt(0)" ::: "memory");
      }
      __builtin_amdgcn_sched_barrier(0);
      __builtin_amdgcn_s_barrier();
    }
  }

#pragma unroll
  for (int mt = 0; mt < 8; mt++) {
#pragma unroll
    for (int r = 0; r < 4; r++) {
      const int row = bm + wm + mt * 16 + quad * 4 + r;
      const size_t base = (size_t)row * N;
#pragma unroll
      for (int nt = 0; nt < 4; nt++) {
        const int col = bn + wn + nt * 16 + l16;
        float v = acc[mt][nt][r];
        if (EPI == 1)      v = Res[base + col] + v * Scale[col];
        else if (EPI == 2) { v = fmaxf(v, 0.f); v = v * v; }
        if constexpr (sizeof(OutT) == 2) C[base + col] = f2bf(v);
        else                             C[base + col] = v;
      }
    }
  }
}

// ---------------------------------------------------------------------------
// Row RMSNorm over 2048 (f32 in, bf16 out), one block (256 thr) per row.
// ---------------------------------------------------------------------------
__global__ __launch_bounds__(256)
void rmsnorm_k(const float* __restrict__ X, ushort_t* __restrict__ Y) {
  const int row = blockIdx.x, tid = threadIdx.x;
  const float* x = X + (size_t)row * 2048 + tid * 8;
  float v[8];
  *(float4*)&v[0] = *(const float4*)x;
  *(float4*)&v[4] = *(const float4*)(x + 4);
  float ss = 0.f;
#pragma unroll
  for (int i = 0; i < 8; i++) ss += v[i] * v[i];
  for (int o = 32; o; o >>= 1) ss += __shfl_xor(ss, o, 64);
  __shared__ float red[4];
  if ((tid & 63) == 0) red[tid >> 6] = ss;
  __syncthreads();
  const float tot = red[0] + red[1] + red[2] + red[3];
  const float sc = rsqrtf(tot * (1.0f / 2048.0f) + 1e-6f);
  u32x4 o4;
#pragma unroll
  for (int i = 0; i < 4; i++)
    o4[i] = (unsigned int)f2bf(v[2 * i] * sc) | ((unsigned int)f2bf(v[2 * i + 1] * sc) << 16);
  *(u32x4*)(Y + (size_t)row * 2048 + tid * 8) = o4;
}

// ---------------------------------------------------------------------------
// QK-norm + rotary. One wave per (token, head). Lane l owns pair (l, l+64).
// ---------------------------------------------------------------------------
__global__ __launch_bounds__(256)
void rotary_qk(ushort_t* __restrict__ qkv, float* __restrict__ kout,
               float* __restrict__ vout) {
  const int tid = threadIdx.x, wave = tid >> 6, lane = tid & 63;
  const int unit = blockIdx.x * 4 + wave;
  const int token = unit >> 4, h = unit & 15;
  const int t = token & 2047;
  ushort_t* qrow = qkv + (size_t)token * 6144 + h * 128;
  ushort_t* krow = qrow + 2048;
  const ushort_t* vrow = qrow + 4096;
  float q1 = bf2f(qrow[lane]), q2 = bf2f(qrow[lane + 64]);
  float k1 = bf2f(krow[lane]), k2 = bf2f(krow[lane + 64]);
  float sq = q1 * q1 + q2 * q2, sk = k1 * k1 + k2 * k2;
  for (int o = 32; o; o >>= 1) { sq += __shfl_xor(sq, o, 64); sk += __shfl_xor(sk, o, 64); }
  const float rq = rsqrtf(sq * (1.f / 128.f) + 1e-6f);
  const float rk = rsqrtf(sk * (1.f / 128.f) + 1e-6f);
  q1 *= rq; q2 *= rq; k1 *= rk; k2 *= rk;
  float c = 1.f, s = 0.f;
  if (lane < 32) {
    const float f = exp2f((float)lane * (-13.28771237954945f / 31.0f));
    const float th = (float)t * f;
    s = sinf(th); c = cosf(th);
  }
  const float qy1 = q1 * c + q2 * s, qy2 = -q1 * s + q2 * c;
  const float ky1 = k1 * c + k2 * s, ky2 = -k1 * s + k2 * c;
  const unsigned short qb1 = f2bf(qy1), qb2 = f2bf(qy2);
  const unsigned short kb1 = f2bf(ky1), kb2 = f2bf(ky2);
  qrow[lane] = qb1; qrow[lane + 64] = qb2;
  krow[lane] = kb1; krow[lane + 64] = kb2;
  float* ko = kout + (size_t)token * 2048 + h * 128;
  ko[lane] = bf2f(kb1); ko[lane + 64] = bf2f(kb2);
  float* vo = vout + (size_t)token * 2048 + h * 128;
  vo[lane] = bf2f(vrow[lane]); vo[lane + 64] = bf2f(vrow[lane + 64]);
}

// ---------------------------------------------------------------------------
// V transpose per (b,h): qkv v-section [T,128] -> Vt [128,T] (bf16).
// ---------------------------------------------------------------------------
__global__ __launch_bounds__(256)
void transpose_v(const ushort_t* __restrict__ qkv, ushort_t* __restrict__ vt) {
  __shared__ ushort_t tile[128][136];
  const int t16 = blockIdx.x, h = blockIdx.y, b = blockIdx.z;
  const int tid = threadIdx.x;
#pragma unroll
  for (int i = 0; i < 8; i++) {
    const int c = i * 256 + tid;
    const int row = c >> 4, cc = (c & 15) * 8;
    const size_t tok = (size_t)(b * 2048 + t16 * 128 + row);
    u32x4 d = *(const u32x4*)(qkv + tok * 6144 + 4096 + h * 128 + cc);
    *(u32x4*)&tile[row][cc] = d;
  }
  __syncthreads();
#pragma unroll
  for (int i = 0; i < 8; i++) {
    const int c = i * 256 + tid;
    const int hr = c >> 4, tc = (c & 15) * 8;
    u32x4 o;
#pragma unroll
    for (int j = 0; j < 4; j++) {
      const unsigned int lo = tile[tc + 2 * j][hr];
      const unsigned int hi = tile[tc + 2 * j + 1][hr];
      o[j] = lo | (hi << 16);
    }
    *(u32x4*)(vt + ((size_t)(b * 16 + h) * 128 + hr) * 2048 + t16 * 128 + tc) = o;
  }
}

// ---------------------------------------------------------------------------
// Causal flash attention. R3: double-buffered K/V with async staging —
// tile t+1's global_load_lds issued BEFORE tile t's compute (T3-minimum
// 2-deep pipeline); ONE __syncthreads per tile (its implicit vmcnt(0)
// drains a prefetch that had the whole compute phase in flight, and fences
// buffer reuse). LDS 48->80 KB (2 blocks/CU). Swizzle/remap from R1 kept.
// ---------------------------------------------------------------------------
__global__ __launch_bounds__(256)
void attn_k(const ushort_t* __restrict__ qkv, const ushort_t* __restrict__ vt,
            ushort_t* __restrict__ obuf) {
  __shared__ ushort_t kbuf[2][64 * 128];
  __shared__ ushort_t vbuf[2][128 * 64];
  __shared__ ushort_t pbuf[4][32 * 64];
  const int lin = blockIdx.x + (blockIdx.y << 4) + (blockIdx.z << 8);
  const int wid = ((lin & 7) << 7) + (lin >> 3);   // 1024 % 8 == 0 -> bijective
  const int qb = 15 - (wid & 15);
  const int h  = (wid >> 4) & 15;
  const int b  = wid >> 8;
  const int tid = threadIdx.x, wave = tid >> 6, lane = tid & 63;
  const int quad = lane >> 4, l16 = lane & 15;
  const float SCALE = 0.08838834764831845f;  // 1/sqrt(128)

  const int nkt = qb * 2 + 2;
  const size_t kb0 = (size_t)(b * 2048) * 6144 + 2048 + h * 128;
  const size_t vt0 = (size_t)(b * 16 + h) * 128 * 2048;

  // stage one K-tile (64 K-rows + 64 V-cols) into buffer bu.
  auto stage = [&](int bu, int kt) {
#pragma unroll
    for (int i = 0; i < 4; i++) {
      const int c = i * 256 + tid;
      const int kr = c >> 4, ck = c & 15;
      gld_lds16(qkv + kb0 + (size_t)(kt * 64 + kr) * 6144 + (ck ^ (kr & 7)) * 8,
                &kbuf[bu][c * 8]);
      const int hr = c >> 3, cv = c & 7;
      gld_lds16(vt + vt0 + (size_t)hr * 2048 + kt * 64 + (cv ^ (hr & 7)) * 8,
                &vbuf[bu][c * 8]);
    }
  };

  bf16x8 qf[2][4];
#pragma unroll
  for (int mt = 0; mt < 2; mt++)
#pragma unroll
    for (int ks = 0; ks < 4; ks++) {
      const int tok = b * 2048 + qb * 128 + wave * 32 + mt * 16 + l16;
      qf[mt][ks] = *(const bf16x8*)(qkv + (size_t)tok * 6144 + h * 128 + ks * 32 + quad * 8);
    }
  f32x4 O[2][8] = {};
  float mrow[2][4], lrow[2][4];
#pragma unroll
  for (int mt = 0; mt < 2; mt++)
#pragma unroll
    for (int r = 0; r < 4; r++) { mrow[mt][r] = -__builtin_inff(); lrow[mt][r] = 0.f; }

  stage(0, 0);
  __syncthreads();   // drain prologue stage

  for (int kt = 0; kt < nkt; kt++) {
    const int cur = kt & 1;
    // issue next tile's loads FIRST: they fly under this tile's compute.
    if (kt + 1 < nkt) stage(cur ^ 1, kt + 1);
    __builtin_amdgcn_sched_barrier(0);   // pin issue point above compute

    f32x4 S[2][4] = {};
#pragma unroll
    for (int ks = 0; ks < 4; ks++) {
      bf16x8 kf[4];
#pragma unroll
      for (int nt = 0; nt < 4; nt++) {
        const int krow = nt * 16 + l16;
        kf[nt] = *(const bf16x8*)&kbuf[cur][krow * 128 + (swz(krow, ks * 64 + quad * 16) >> 1)];
      }
#pragma unroll
      for (int mt = 0; mt < 2; mt++)
#pragma unroll
        for (int nt = 0; nt < 4; nt++)
          S[mt][nt] = __builtin_amdgcn_mfma_f32_16x16x32_bf16(qf[mt][ks], kf[nt], S[mt][nt], 0, 0, 0);
    }
    float alpha[2][4];
#pragma unroll
    for (int mt = 0; mt < 2; mt++) {
#pragma unroll
      for (int r = 0; r < 4; r++) {
        const int qr = qb * 128 + wave * 32 + mt * 16 + quad * 4 + r;
        float mx = -__builtin_inff();
#pragma unroll
        for (int nt = 0; nt < 4; nt++) {
          const int kc = kt * 64 + nt * 16 + l16;
          float sv = S[mt][nt][r] * SCALE;
          if (kc > qr) sv = -__builtin_inff();
          S[mt][nt][r] = sv;
          mx = fmaxf(mx, sv);
        }
        for (int o = 1; o < 16; o <<= 1) mx = fmaxf(mx, __shfl_xor(mx, o, 64));
        const float mnew = fmaxf(mrow[mt][r], mx);
        float rs = 0.f;
        const int prow = mt * 16 + quad * 4 + r;
#pragma unroll
        for (int nt = 0; nt < 4; nt++) {
          const float p = exp2f((S[mt][nt][r] - mnew) * LOG2E);
          rs += p;
          pbuf[wave][prow * 64 + (swz(prow, (nt * 16 + l16) * 2) >> 1)] = f2bf(p);
        }
        for (int o = 1; o < 16; o <<= 1) rs += __shfl_xor(rs, o, 64);
        const float a = exp2f((mrow[mt][r] - mnew) * LOG2E);
        alpha[mt][r] = a;
        lrow[mt][r] = lrow[mt][r] * a + rs;
        mrow[mt][r] = mnew;
      }
    }
#pragma unroll
    for (int mt = 0; mt < 2; mt++)
#pragma unroll
      for (int nto = 0; nto < 8; nto++)
#pragma unroll
        for (int r = 0; r < 4; r++)
          O[mt][nto][r] *= alpha[mt][r];
#pragma unroll
    for (int ks = 0; ks < 2; ks++) {
      bf16x8 pa[2];
#pragma unroll
      for (int mt = 0; mt < 2; mt++) {
        const int parow = mt * 16 + l16;
        pa[mt] = *(const bf16x8*)&pbuf[wave][parow * 64 + (swz(parow, ks * 64 + quad * 16) >> 1)];
      }
#pragma unroll
      for (int nto = 0; nto < 8; nto++) {
        const int vrow = nto * 16 + l16;
        const bf16x8 vb = *(const bf16x8*)&vbuf[cur][vrow * 64 + (swz(vrow, ks * 64 + quad * 16) >> 1)];
#pragma unroll
        for (int mt = 0; mt < 2; mt++)
          O[mt][nto] = __builtin_amdgcn_mfma_f32_16x16x32_bf16(pa[mt], vb, O[mt][nto], 0, 0, 0);
      }
    }
    // ONE barrier per tile: implicit vmcnt(0)+lgkmcnt(0) drains the prefetch
    // (in flight for the whole compute phase) and fences buf[cur] reuse.
    __syncthreads();
  }
#pragma unroll
  for (int mt = 0; mt < 2; mt++)
#pragma unroll
    for (int r = 0; r < 4; r++) {
      const float inv = 1.0f / lrow[mt][r];
      const int row = b * 2048 + qb * 128 + wave * 32 + mt * 16 + quad * 4 + r;
      const size_t base = (size_t)row * 2048 + h * 128;
#pragma unroll
      for (int nto = 0; nto < 8; nto++)
        obuf[base + nto * 16 + l16] = f2bf(O[mt][nto][r] * inv);
    }
}

// ---------------------------------------------------------------------------
extern "C" void kernel_launch(void* const* d_in, const int* in_sizes, int n_in,
                              void* d_out, int out_size, void* d_ws, size_t ws_size,
                              hipStream_t stream) {
  (void)in_sizes; (void)n_in; (void)out_size; (void)ws_size;
  const float* x       = (const float*)d_in[0];
  const float* qkv_w   = (const float*)d_in[1];
  const float* o_w     = (const float*)d_in[2];
  const float* o_scale = (const float*)d_in[3];
  const float* w1      = (const float*)d_in[4];
  const float* w2      = (const float*)d_in[5];
  const float* mscale  = (const float*)d_in[6];
  float* outx = (float*)d_out;                       // [4,2048,2048]   = 16777216
  float* outk = outx + (size_t)16777216;             // [4,2048,16,128] = 16777216
  float* outv = outk + (size_t)16777216;             // [4,2048,16,128] = 16777216

  char* ws = (char*)d_ws;
  ushort_t* qkv    = (ushort_t*)(ws + 0);            // 96 MB  [8192,6144] bf16
  ushort_t* vt     = (ushort_t*)(ws + 100663296);    // 32 MB  [4,16,128,2048] bf16
  ushort_t* xn     = (ushort_t*)(ws + 134217728);    // 32 MB  bf16 (xn / o / xn2 serial reuse)
  float*    x1     = (float*)   (ws + 167772160);    // 64 MB  f32
  ushort_t* qkv_wb = (ushort_t*)(ws + 234881024);    // 24 MB  bf16
  ushort_t* o_wb   = (ushort_t*)(ws + 260046848);    //  8 MB
  ushort_t* w1b    = (ushort_t*)(ws + 268435456);    // 32 MB
  ushort_t* w2b    = (ushort_t*)(ws + 301989888);    // 32 MB  (total 320 MB)
  ushort_t* hbuf   = (ushort_t*)(ws + 0);            // 128 MB overlays qkv+vt (dead after attn)

  cvt_bf16<<<12288, 256, 0, stream>>>(qkv_w, qkv_wb, 12582912);
  cvt_bf16<<<4096,  256, 0, stream>>>(o_w,   o_wb,   4194304);
  cvt_bf16<<<16384, 256, 0, stream>>>(w1,    w1b,    16777216);
  cvt_bf16<<<16384, 256, 0, stream>>>(w2,    w2b,    16777216);

  rmsnorm_k<<<8192, 256, 0, stream>>>(x, xn);
  gemm_bt256<0, ushort_t><<<dim3(24, 32), 512, 0, stream>>>(xn, qkv_wb, qkv, nullptr, nullptr, 8192, 6144, 2048);
  rotary_qk<<<32768, 256, 0, stream>>>(qkv, outk, outv);
  transpose_v<<<dim3(16, 16, 4), 256, 0, stream>>>(qkv, vt);
  attn_k<<<dim3(16, 16, 4), 256, 0, stream>>>(qkv, vt, xn /* o */);
  gemm_bt256<1, float><<<dim3(8, 32), 512, 0, stream>>>(xn /* o */, o_wb, x1, x, o_scale, 8192, 2048, 2048);
  rmsnorm_k<<<8192, 256, 0, stream>>>(x1, xn);
  gemm_bt256<2, ushort_t><<<dim3(32, 32), 512, 0, stream>>>(xn, w1b, hbuf, nullptr, nullptr, 8192, 8192, 2048);
  gemm_bt256<1, float><<<dim3(8, 32), 512, 0, stream>>>(hbuf, w2b, outx, x1, mscale, 8192, 2048, 8192);
}

// Round 4
// 1554.684 us; speedup vs baseline: 1.4381x; 1.1276x over previous
//
#include <hip/hip_runtime.h>
#include <hip/hip_bf16.h>
#include <cstdint>
#include <cstddef>

typedef unsigned short ushort_t;
typedef __attribute__((ext_vector_type(8))) __bf16 bf16x8;
typedef __attribute__((ext_vector_type(4))) float f32x4;
typedef __attribute__((ext_vector_type(4))) unsigned int u32x4;
typedef __attribute__((ext_vector_type(2))) unsigned int u32x2;

#define LOG2E 1.44269504088896f

__device__ __forceinline__ float bf2f(unsigned short u) {
  union { unsigned int i; float f; } w; w.i = ((unsigned int)u) << 16; return w.f;
}
__device__ __forceinline__ unsigned short f2bf(float f) {
  union { float f; unsigned int i; } w; w.f = f;
  unsigned int u = w.i;
  u += 0x7fffu + ((u >> 16) & 1);   // RNE
  return (unsigned short)(u >> 16);
}
__device__ __forceinline__ void gld_lds16(const void* g, void* l) {
  __builtin_amdgcn_global_load_lds(
      (const __attribute__((address_space(1))) unsigned int*)g,
      (__attribute__((address_space(3))) unsigned int*)l, 16, 0, 0);
}
// XOR-swizzle of a byte offset within a row (rows of 128B/256B): spreads the
// quad's 16-row column reads across 8 distinct 16B bank slots.
__device__ __forceinline__ int swz(int row, int byteoff) {
  return byteoff ^ ((row & 7) << 4);
}

// ---------------------------------------------------------------------------
// f32 -> bf16 weight conversion, 4 elems/thread.
// ---------------------------------------------------------------------------
__global__ __launch_bounds__(256)
void cvt_bf16(const float* __restrict__ in, ushort_t* __restrict__ outp, int n) {
  const int i = (blockIdx.x * 256 + threadIdx.x) * 4;
  if (i >= n) return;
  const float4 d = *(const float4*)(in + i);
  u32x2 o;
  o[0] = (unsigned int)f2bf(d.x) | ((unsigned int)f2bf(d.y) << 16);
  o[1] = (unsigned int)f2bf(d.z) | ((unsigned int)f2bf(d.w) << 16);
  *(u32x2*)(outp + i) = o;
}

// ---------------------------------------------------------------------------
// Phased 256x256 bf16 GEMM (R2 structure, unchanged): BK=64, 8 waves (2Mx4N),
// double-buffered LDS, 4 phases/K-tile, single vmcnt(0)/tile, T2 swizzle
// both-sides, T1 XCD remap, T5 setprio.
// ---------------------------------------------------------------------------
__device__ __forceinline__ void stage_half(const ushort_t* __restrict__ gsrc,
                                           size_t rstride, ushort_t* ldst, int tid) {
#pragma unroll
  for (int i = 0; i < 2; i++) {
    const int c = i * 512 + tid;
    const int r = c >> 3, col = c & 7;
    gld_lds16(gsrc + (size_t)r * rstride + ((col ^ (r & 7)) << 3), ldst + c * 8);
  }
}

template <int EPI, typename OutT>
__global__ __launch_bounds__(512, 2)
void gemm_bt256(const ushort_t* __restrict__ A, const ushort_t* __restrict__ B,
                OutT* __restrict__ C, const float* __restrict__ Res,
                const float* __restrict__ Scale, int M, int N, int K) {
  __shared__ ushort_t As[2][256 * 64];
  __shared__ ushort_t Bs[2][256 * 64];
  const int tid = threadIdx.x;
  const int wave = tid >> 6, lane = tid & 63;
  const int quad = lane >> 4, l16 = lane & 15;
  const int ntn = N >> 8;
  const int nwg = (M >> 8) * ntn;
  const int lin = blockIdx.y * gridDim.x + blockIdx.x;
  const int wid = (lin & 7) * (nwg >> 3) + (lin >> 3);
  const int bn = (wid % ntn) << 8;
  const int bm = (wid / ntn) << 8;
  const int wm = (wave >> 2) * 128, wn = (wave & 3) * 64;

  f32x4 acc[8][4] = {};

  const ushort_t* aB = A + (size_t)bm * K;
  const ushort_t* bB = B + (size_t)bn * K;
  const int nk = K >> 6;

  stage_half(aB, K, &As[0][0], tid);
  stage_half(aB + (size_t)128 * K, K, &As[0][8192], tid);
  stage_half(bB, K, &Bs[0][0], tid);
  stage_half(bB + (size_t)128 * K, K, &Bs[0][8192], tid);
  asm volatile("s_waitcnt vmcnt(0)" ::: "memory");
  __builtin_amdgcn_sched_barrier(0);
  __builtin_amdgcn_s_barrier();

  for (int t = 0; t < nk; ++t) {
    const int cur = t & 1, nb = cur ^ 1;
    const ushort_t* Ac = &As[cur][0];
    const ushort_t* Bc = &Bs[cur][0];
    const int k0n = (t + 1) << 6;
    const bool pf = (t + 1 < nk);
#pragma unroll
    for (int q = 0; q < 4; q++) {
      const int mh = q >> 1, nh = q & 1;
      bf16x8 af[4][2], bfq[2][2];
#pragma unroll
      for (int j = 0; j < 4; j++) {
        const int row = wm + (mh * 4 + j) * 16 + l16;
#pragma unroll
        for (int ks = 0; ks < 2; ks++)
          af[j][ks] = *(const bf16x8*)&Ac[row * 64 + (swz(row, ks * 64 + quad * 16) >> 1)];
      }
#pragma unroll
      for (int j = 0; j < 2; j++) {
        const int row = wn + (nh * 2 + j) * 16 + l16;
#pragma unroll
        for (int ks = 0; ks < 2; ks++)
          bfq[j][ks] = *(const bf16x8*)&Bc[row * 64 + (swz(row, ks * 64 + quad * 16) >> 1)];
      }
      if (pf) {
        if (q == 0)      stage_half(aB + k0n, K, &As[nb][0], tid);
        else if (q == 1) stage_half(aB + (size_t)128 * K + k0n, K, &As[nb][8192], tid);
        else if (q == 2) {
          stage_half(bB + k0n, K, &Bs[nb][0], tid);
          stage_half(bB + (size_t)128 * K + k0n, K, &Bs[nb][8192], tid);
        }
      }
      __builtin_amdgcn_sched_barrier(0);
      __builtin_amdgcn_s_barrier();
      __builtin_amdgcn_s_setprio(1);
#pragma unroll
      for (int j = 0; j < 4; j++)
#pragma unroll
        for (int n2 = 0; n2 < 2; n2++)
#pragma unroll
          for (int ks = 0; ks < 2; ks++)
            acc[mh * 4 + j][nh * 2 + n2] = __builtin_amdgcn_mfma_f32_16x16x32_bf16(
                af[j][ks], bfq[n2][ks], acc[mh * 4 + j][nh * 2 + n2], 0, 0, 0);
      __builtin_amdgcn_s_setprio(0);
      if (q == 3) {
        asm volatile("s_waitcnt vmcnt(0)" ::: "memory");
      }
      __builtin_amdgcn_sched_barrier(0);
      __builtin_amdgcn_s_barrier();
    }
  }

#pragma unroll
  for (int mt = 0; mt < 8; mt++) {
#pragma unroll
    for (int r = 0; r < 4; r++) {
      const int row = bm + wm + mt * 16 + quad * 4 + r;
      const size_t base = (size_t)row * N;
#pragma unroll
      for (int nt = 0; nt < 4; nt++) {
        const int col = bn + wn + nt * 16 + l16;
        float v = acc[mt][nt][r];
        if (EPI == 1)      v = Res[base + col] + v * Scale[col];
        else if (EPI == 2) { v = fmaxf(v, 0.f); v = v * v; }
        if constexpr (sizeof(OutT) == 2) C[base + col] = f2bf(v);
        else                             C[base + col] = v;
      }
    }
  }
}

// ---------------------------------------------------------------------------
// Row RMSNorm over 2048 (f32 in, bf16 out), one block (256 thr) per row.
// ---------------------------------------------------------------------------
__global__ __launch_bounds__(256)
void rmsnorm_k(const float* __restrict__ X, ushort_t* __restrict__ Y) {
  const int row = blockIdx.x, tid = threadIdx.x;
  const float* x = X + (size_t)row * 2048 + tid * 8;
  float v[8];
  *(float4*)&v[0] = *(const float4*)x;
  *(float4*)&v[4] = *(const float4*)(x + 4);
  float ss = 0.f;
#pragma unroll
  for (int i = 0; i < 8; i++) ss += v[i] * v[i];
  for (int o = 32; o; o >>= 1) ss += __shfl_xor(ss, o, 64);
  __shared__ float red[4];
  if ((tid & 63) == 0) red[tid >> 6] = ss;
  __syncthreads();
  const float tot = red[0] + red[1] + red[2] + red[3];
  const float sc = rsqrtf(tot * (1.0f / 2048.0f) + 1e-6f);
  u32x4 o4;
#pragma unroll
  for (int i = 0; i < 4; i++)
    o4[i] = (unsigned int)f2bf(v[2 * i] * sc) | ((unsigned int)f2bf(v[2 * i + 1] * sc) << 16);
  *(u32x4*)(Y + (size_t)row * 2048 + tid * 8) = o4;
}

// ---------------------------------------------------------------------------
// QK-norm + rotary. One wave per (token, head). Lane l owns pair (l, l+64).
// ---------------------------------------------------------------------------
__global__ __launch_bounds__(256)
void rotary_qk(ushort_t* __restrict__ qkv, float* __restrict__ kout,
               float* __restrict__ vout) {
  const int tid = threadIdx.x, wave = tid >> 6, lane = tid & 63;
  const int unit = blockIdx.x * 4 + wave;
  const int token = unit >> 4, h = unit & 15;
  const int t = token & 2047;
  ushort_t* qrow = qkv + (size_t)token * 6144 + h * 128;
  ushort_t* krow = qrow + 2048;
  const ushort_t* vrow = qrow + 4096;
  float q1 = bf2f(qrow[lane]), q2 = bf2f(qrow[lane + 64]);
  float k1 = bf2f(krow[lane]), k2 = bf2f(krow[lane + 64]);
  float sq = q1 * q1 + q2 * q2, sk = k1 * k1 + k2 * k2;
  for (int o = 32; o; o >>= 1) { sq += __shfl_xor(sq, o, 64); sk += __shfl_xor(sk, o, 64); }
  const float rq = rsqrtf(sq * (1.f / 128.f) + 1e-6f);
  const float rk = rsqrtf(sk * (1.f / 128.f) + 1e-6f);
  q1 *= rq; q2 *= rq; k1 *= rk; k2 *= rk;
  float c = 1.f, s = 0.f;
  if (lane < 32) {
    const float f = exp2f((float)lane * (-13.28771237954945f / 31.0f));
    const float th = (float)t * f;
    s = sinf(th); c = cosf(th);
  }
  const float qy1 = q1 * c + q2 * s, qy2 = -q1 * s + q2 * c;
  const float ky1 = k1 * c + k2 * s, ky2 = -k1 * s + k2 * c;
  const unsigned short qb1 = f2bf(qy1), qb2 = f2bf(qy2);
  const unsigned short kb1 = f2bf(ky1), kb2 = f2bf(ky2);
  qrow[lane] = qb1; qrow[lane + 64] = qb2;
  krow[lane] = kb1; krow[lane + 64] = kb2;
  float* ko = kout + (size_t)token * 2048 + h * 128;
  ko[lane] = bf2f(kb1); ko[lane + 64] = bf2f(kb2);
  float* vo = vout + (size_t)token * 2048 + h * 128;
  vo[lane] = bf2f(vrow[lane]); vo[lane + 64] = bf2f(vrow[lane + 64]);
}

// ---------------------------------------------------------------------------
// V transpose per (b,h): qkv v-section [T,128] -> Vt [128,T] (bf16).
// ---------------------------------------------------------------------------
__global__ __launch_bounds__(256)
void transpose_v(const ushort_t* __restrict__ qkv, ushort_t* __restrict__ vt) {
  __shared__ ushort_t tile[128][136];
  const int t16 = blockIdx.x, h = blockIdx.y, b = blockIdx.z;
  const int tid = threadIdx.x;
#pragma unroll
  for (int i = 0; i < 8; i++) {
    const int c = i * 256 + tid;
    const int row = c >> 4, cc = (c & 15) * 8;
    const size_t tok = (size_t)(b * 2048 + t16 * 128 + row);
    u32x4 d = *(const u32x4*)(qkv + tok * 6144 + 4096 + h * 128 + cc);
    *(u32x4*)&tile[row][cc] = d;
  }
  __syncthreads();
#pragma unroll
  for (int i = 0; i < 8; i++) {
    const int c = i * 256 + tid;
    const int hr = c >> 4, tc = (c & 15) * 8;
    u32x4 o;
#pragma unroll
    for (int j = 0; j < 4; j++) {
      const unsigned int lo = tile[tc + 2 * j][hr];
      const unsigned int hi = tile[tc + 2 * j + 1][hr];
      o[j] = lo | (hi << 16);
    }
    *(u32x4*)(vt + ((size_t)(b * 16 + h) * 128 + hr) * 2048 + t16 * 128 + tc) = o;
  }
}

// ---------------------------------------------------------------------------
// Causal flash attention. R4: FIXED-max softmax. QK-norm bounds
// |q.k|*scale <= sqrt(128) ~= 11.32 (rotary is norm-preserving, rmsnorm eps
// only shrinks), so P = exp(S - 11.5) is exact softmax up to a constant that
// cancels in O = sum(P V)/sum(P). This deletes the per-tile max reduce
// (32 shfls), the per-tile sum reduce (32 shfls -> per-lane partials, ONE
// epilogue reduce), mrow/alpha tracking, and the O-rescale pass. The 4-deep
// dependent ds_swizzle chains that serialized the DS pipe are gone.
// R3 prefetch pipeline + R1 swizzles/remap kept.
// ---------------------------------------------------------------------------
__global__ __launch_bounds__(256)
void attn_k(const ushort_t* __restrict__ qkv, const ushort_t* __restrict__ vt,
            ushort_t* __restrict__ obuf) {
  __shared__ ushort_t kbuf[2][64 * 128];
  __shared__ ushort_t vbuf[2][128 * 64];
  __shared__ ushort_t pbuf[4][32 * 64];
  const int lin = blockIdx.x + (blockIdx.y << 4) + (blockIdx.z << 8);
  const int wid = ((lin & 7) << 7) + (lin >> 3);   // 1024 % 8 == 0 -> bijective
  const int qb = 15 - (wid & 15);
  const int h  = (wid >> 4) & 15;
  const int b  = wid >> 8;
  const int tid = threadIdx.x, wave = tid >> 6, lane = tid & 63;
  const int quad = lane >> 4, l16 = lane & 15;
  // exp(S*SCALE - FM) = exp2(S*SCALE_L2E - FML2); FM=11.5 > sqrt(128) bound.
  const float SCALE_L2E = 0.08838834764831845f * 1.44269504088896f;
  const float FML2 = 11.5f * 1.44269504088896f;

  const int nkt = qb * 2 + 2;
  const size_t kb0 = (size_t)(b * 2048) * 6144 + 2048 + h * 128;
  const size_t vt0 = (size_t)(b * 16 + h) * 128 * 2048;

  auto stage = [&](int bu, int kt) {
#pragma unroll
    for (int i = 0; i < 4; i++) {
      const int c = i * 256 + tid;
      const int kr = c >> 4, ck = c & 15;
      gld_lds16(qkv + kb0 + (size_t)(kt * 64 + kr) * 6144 + (ck ^ (kr & 7)) * 8,
                &kbuf[bu][c * 8]);
      const int hr = c >> 3, cv = c & 7;
      gld_lds16(vt + vt0 + (size_t)hr * 2048 + kt * 64 + (cv ^ (hr & 7)) * 8,
                &vbuf[bu][c * 8]);
    }
  };

  bf16x8 qf[2][4];
#pragma unroll
  for (int mt = 0; mt < 2; mt++)
#pragma unroll
    for (int ks = 0; ks < 4; ks++) {
      const int tok = b * 2048 + qb * 128 + wave * 32 + mt * 16 + l16;
      qf[mt][ks] = *(const bf16x8*)(qkv + (size_t)tok * 6144 + h * 128 + ks * 32 + quad * 8);
    }
  f32x4 O[2][8] = {};
  float lrow[2][4] = {};   // per-lane PARTIAL row sums (reduced once at end)

  stage(0, 0);
  __syncthreads();   // drain prologue stage

  for (int kt = 0; kt < nkt; kt++) {
    const int cur = kt & 1;
    if (kt + 1 < nkt) stage(cur ^ 1, kt + 1);
    __builtin_amdgcn_sched_barrier(0);   // pin issue point above compute

    f32x4 S[2][4] = {};
#pragma unroll
    for (int ks = 0; ks < 4; ks++) {
      bf16x8 kf[4];
#pragma unroll
      for (int nt = 0; nt < 4; nt++) {
        const int krow = nt * 16 + l16;
        kf[nt] = *(const bf16x8*)&kbuf[cur][krow * 128 + (swz(krow, ks * 64 + quad * 16) >> 1)];
      }
#pragma unroll
      for (int mt = 0; mt < 2; mt++)
#pragma unroll
        for (int nt = 0; nt < 4; nt++)
          S[mt][nt] = __builtin_amdgcn_mfma_f32_16x16x32_bf16(qf[mt][ks], kf[nt], S[mt][nt], 0, 0, 0);
    }
    // fixed-max softmax: p = exp2(S*SCALE_L2E - FML2); no reduces, no rescale.
#pragma unroll
    for (int mt = 0; mt < 2; mt++) {
#pragma unroll
      for (int r = 0; r < 4; r++) {
        const int qr = qb * 128 + wave * 32 + mt * 16 + quad * 4 + r;
        const int prow = mt * 16 + quad * 4 + r;
        float rs = 0.f;
#pragma unroll
        for (int nt = 0; nt < 4; nt++) {
          const int kc = kt * 64 + nt * 16 + l16;
          float p = (kc > qr) ? 0.f : exp2f(fmaf(S[mt][nt][r], SCALE_L2E, -FML2));
          rs += p;
          pbuf[wave][prow * 64 + (swz(prow, (nt * 16 + l16) * 2) >> 1)] = f2bf(p);
        }
        lrow[mt][r] += rs;
      }
    }
#pragma unroll
    for (int ks = 0; ks < 2; ks++) {
      bf16x8 pa[2];
#pragma unroll
      for (int mt = 0; mt < 2; mt++) {
        const int parow = mt * 16 + l16;
        pa[mt] = *(const bf16x8*)&pbuf[wave][parow * 64 + (swz(parow, ks * 64 + quad * 16) >> 1)];
      }
#pragma unroll
      for (int nto = 0; nto < 8; nto++) {
        const int vrow = nto * 16 + l16;
        const bf16x8 vb = *(const bf16x8*)&vbuf[cur][vrow * 64 + (swz(vrow, ks * 64 + quad * 16) >> 1)];
#pragma unroll
        for (int mt = 0; mt < 2; mt++)
          O[mt][nto] = __builtin_amdgcn_mfma_f32_16x16x32_bf16(pa[mt], vb, O[mt][nto], 0, 0, 0);
      }
    }
    __syncthreads();
  }
  // epilogue: ONE 16-lane sum reduce per row, then normalize + store.
#pragma unroll
  for (int mt = 0; mt < 2; mt++)
#pragma unroll
    for (int r = 0; r < 4; r++) {
      float ls = lrow[mt][r];
      for (int o = 1; o < 16; o <<= 1) ls += __shfl_xor(ls, o, 64);
      const float inv = 1.0f / ls;
      const int row = b * 2048 + qb * 128 + wave * 32 + mt * 16 + quad * 4 + r;
      const size_t base = (size_t)row * 2048 + h * 128;
#pragma unroll
      for (int nto = 0; nto < 8; nto++)
        obuf[base + nto * 16 + l16] = f2bf(O[mt][nto][r] * inv);
    }
}

// ---------------------------------------------------------------------------
extern "C" void kernel_launch(void* const* d_in, const int* in_sizes, int n_in,
                              void* d_out, int out_size, void* d_ws, size_t ws_size,
                              hipStream_t stream) {
  (void)in_sizes; (void)n_in; (void)out_size; (void)ws_size;
  const float* x       = (const float*)d_in[0];
  const float* qkv_w   = (const float*)d_in[1];
  const float* o_w     = (const float*)d_in[2];
  const float* o_scale = (const float*)d_in[3];
  const float* w1      = (const float*)d_in[4];
  const float* w2      = (const float*)d_in[5];
  const float* mscale  = (const float*)d_in[6];
  float* outx = (float*)d_out;                       // [4,2048,2048]   = 16777216
  float* outk = outx + (size_t)16777216;             // [4,2048,16,128] = 16777216
  float* outv = outk + (size_t)16777216;             // [4,2048,16,128] = 16777216

  char* ws = (char*)d_ws;
  ushort_t* qkv    = (ushort_t*)(ws + 0);            // 96 MB  [8192,6144] bf16
  ushort_t* vt     = (ushort_t*)(ws + 100663296);    // 32 MB  [4,16,128,2048] bf16
  ushort_t* xn     = (ushort_t*)(ws + 134217728);    // 32 MB  bf16 (xn / o / xn2 serial reuse)
  float*    x1     = (float*)   (ws + 167772160);    // 64 MB  f32
  ushort_t* qkv_wb = (ushort_t*)(ws + 234881024);    // 24 MB  bf16
  ushort_t* o_wb   = (ushort_t*)(ws + 260046848);    //  8 MB
  ushort_t* w1b    = (ushort_t*)(ws + 268435456);    // 32 MB
  ushort_t* w2b    = (ushort_t*)(ws + 301989888);    // 32 MB  (total 320 MB)
  ushort_t* hbuf   = (ushort_t*)(ws + 0);            // 128 MB overlays qkv+vt (dead after attn)

  cvt_bf16<<<12288, 256, 0, stream>>>(qkv_w, qkv_wb, 12582912);
  cvt_bf16<<<4096,  256, 0, stream>>>(o_w,   o_wb,   4194304);
  cvt_bf16<<<16384, 256, 0, stream>>>(w1,    w1b,    16777216);
  cvt_bf16<<<16384, 256, 0, stream>>>(w2,    w2b,    16777216);

  rmsnorm_k<<<8192, 256, 0, stream>>>(x, xn);
  gemm_bt256<0, ushort_t><<<dim3(24, 32), 512, 0, stream>>>(xn, qkv_wb, qkv, nullptr, nullptr, 8192, 6144, 2048);
  rotary_qk<<<32768, 256, 0, stream>>>(qkv, outk, outv);
  transpose_v<<<dim3(16, 16, 4), 256, 0, stream>>>(qkv, vt);
  attn_k<<<dim3(16, 16, 4), 256, 0, stream>>>(qkv, vt, xn /* o */);
  gemm_bt256<1, float><<<dim3(8, 32), 512, 0, stream>>>(xn /* o */, o_wb, x1, x, o_scale, 8192, 2048, 2048);
  rmsnorm_k<<<8192, 256, 0, stream>>>(x1, xn);
  gemm_bt256<2, ushort_t><<<dim3(32, 32), 512, 0, stream>>>(xn, w1b, hbuf, nullptr, nullptr, 8192, 8192, 2048);
  gemm_bt256<1, float><<<dim3(8, 32), 512, 0, stream>>>(hbuf, w2b, outx, x1, mscale, 8192, 2048, 8192);
}

// Round 5
// 1429.043 us; speedup vs baseline: 1.5645x; 1.0879x over previous
//
#include <hip/hip_runtime.h>
#include <hip/hip_bf16.h>
#include <cstdint>
#include <cstddef>

typedef unsigned short ushort_t;
typedef __attribute__((ext_vector_type(8))) __bf16 bf16x8;
typedef __attribute__((ext_vector_type(4))) float f32x4;
typedef __attribute__((ext_vector_type(4))) unsigned int u32x4;
typedef __attribute__((ext_vector_type(2))) unsigned int u32x2;

#define LOG2E 1.44269504088896f

__device__ __forceinline__ float bf2f(unsigned short u) {
  union { unsigned int i; float f; } w; w.i = ((unsigned int)u) << 16; return w.f;
}
__device__ __forceinline__ unsigned short f2bf(float f) {
  union { float f; unsigned int i; } w; w.f = f;
  unsigned int u = w.i;
  u += 0x7fffu + ((u >> 16) & 1);   // RNE
  return (unsigned short)(u >> 16);
}
__device__ __forceinline__ void gld_lds16(const void* g, void* l) {
  __builtin_amdgcn_global_load_lds(
      (const __attribute__((address_space(1))) unsigned int*)g,
      (__attribute__((address_space(3))) unsigned int*)l, 16, 0, 0);
}
// XOR-swizzle of a byte offset within a row (rows of 128B/256B): spreads the
// quad's 16-row column reads across 8 distinct 16B bank slots.
__device__ __forceinline__ int swz(int row, int byteoff) {
  return byteoff ^ ((row & 7) << 4);
}

// ---------------------------------------------------------------------------
// f32 -> bf16 weight conversion, 4 elems/thread.
// ---------------------------------------------------------------------------
__global__ __launch_bounds__(256)
void cvt_bf16(const float* __restrict__ in, ushort_t* __restrict__ outp, int n) {
  const int i = (blockIdx.x * 256 + threadIdx.x) * 4;
  if (i >= n) return;
  const float4 d = *(const float4*)(in + i);
  u32x2 o;
  o[0] = (unsigned int)f2bf(d.x) | ((unsigned int)f2bf(d.y) << 16);
  o[1] = (unsigned int)f2bf(d.z) | ((unsigned int)f2bf(d.w) << 16);
  *(u32x2*)(outp + i) = o;
}

// ---------------------------------------------------------------------------
// Phased 256x256 bf16 GEMM. R5: LDS-read dedup. Old 4-quadrant loop read
// each A/B fragment TWICE (48 ds_read_b128/wave/tile, 384KB/CU/tile ->
// DS-pipe-bound, MfmaUtil 37%). New: 2 phases by M-half; B-frags read ONCE
// (held in regs across phases), A-frags once each -> 24 reads/wave/tile,
// barriers 8 -> 3 per tile. Prefetch (A-halves in phase A, B-halves in
// phase B, single vmcnt(0) drain at tile end), T2 swizzle, T1 remap,
// T5 setprio unchanged.
// EPI: 0 = bf16 store, 1 = f32 store Res + C*Scale[col], 2 = bf16 relu(C)^2
// ---------------------------------------------------------------------------
__device__ __forceinline__ void stage_half(const ushort_t* __restrict__ gsrc,
                                           size_t rstride, ushort_t* ldst, int tid) {
#pragma unroll
  for (int i = 0; i < 2; i++) {
    const int c = i * 512 + tid;
    const int r = c >> 3, col = c & 7;
    gld_lds16(gsrc + (size_t)r * rstride + ((col ^ (r & 7)) << 3), ldst + c * 8);
  }
}

template <int EPI, typename OutT>
__global__ __launch_bounds__(512, 2)
void gemm_bt256(const ushort_t* __restrict__ A, const ushort_t* __restrict__ B,
                OutT* __restrict__ C, const float* __restrict__ Res,
                const float* __restrict__ Scale, int M, int N, int K) {
  __shared__ ushort_t As[2][256 * 64];
  __shared__ ushort_t Bs[2][256 * 64];
  const int tid = threadIdx.x;
  const int wave = tid >> 6, lane = tid & 63;
  const int quad = lane >> 4, l16 = lane & 15;
  const int ntn = N >> 8;
  const int nwg = (M >> 8) * ntn;
  const int lin = blockIdx.y * gridDim.x + blockIdx.x;
  const int wid = (lin & 7) * (nwg >> 3) + (lin >> 3);
  const int bn = (wid % ntn) << 8;
  const int bm = (wid / ntn) << 8;
  const int wm = (wave >> 2) * 128, wn = (wave & 3) * 64;

  f32x4 acc[8][4] = {};

  const ushort_t* aB = A + (size_t)bm * K;
  const ushort_t* bB = B + (size_t)bn * K;
  const int nk = K >> 6;

  stage_half(aB, K, &As[0][0], tid);
  stage_half(aB + (size_t)128 * K, K, &As[0][8192], tid);
  stage_half(bB, K, &Bs[0][0], tid);
  stage_half(bB + (size_t)128 * K, K, &Bs[0][8192], tid);
  asm volatile("s_waitcnt vmcnt(0)" ::: "memory");
  __builtin_amdgcn_sched_barrier(0);
  __builtin_amdgcn_s_barrier();

  for (int t = 0; t < nk; ++t) {
    const int cur = t & 1, nb = cur ^ 1;
    const ushort_t* Ac = &As[cur][0];
    const ushort_t* Bc = &Bs[cur][0];
    const int k0n = (t + 1) << 6;
    const bool pf = (t + 1 < nk);

    // ---- phase A: all 8 B-frags (kept in regs for both phases) + A mh=0 ----
    bf16x8 bfr[4][2], af[4][2];
#pragma unroll
    for (int n = 0; n < 4; n++) {
      const int row = wn + n * 16 + l16;
#pragma unroll
      for (int ks = 0; ks < 2; ks++)
        bfr[n][ks] = *(const bf16x8*)&Bc[row * 64 + (swz(row, ks * 64 + quad * 16) >> 1)];
    }
#pragma unroll
    for (int j = 0; j < 4; j++) {
      const int row = wm + j * 16 + l16;
#pragma unroll
      for (int ks = 0; ks < 2; ks++)
        af[j][ks] = *(const bf16x8*)&Ac[row * 64 + (swz(row, ks * 64 + quad * 16) >> 1)];
    }
    if (pf) {
      stage_half(aB + k0n, K, &As[nb][0], tid);
      stage_half(aB + (size_t)128 * K + k0n, K, &As[nb][8192], tid);
    }
    __builtin_amdgcn_sched_barrier(0);
    __builtin_amdgcn_s_barrier();
    __builtin_amdgcn_s_setprio(1);
#pragma unroll
    for (int j = 0; j < 4; j++)
#pragma unroll
      for (int n = 0; n < 4; n++)
#pragma unroll
        for (int ks = 0; ks < 2; ks++)
          acc[j][n] = __builtin_amdgcn_mfma_f32_16x16x32_bf16(af[j][ks], bfr[n][ks], acc[j][n], 0, 0, 0);
    __builtin_amdgcn_s_setprio(0);

    // ---- phase B: A mh=1 (B-frags reused from registers) ----
    bf16x8 ag[4][2];
#pragma unroll
    for (int j = 0; j < 4; j++) {
      const int row = wm + 64 + j * 16 + l16;
#pragma unroll
      for (int ks = 0; ks < 2; ks++)
        ag[j][ks] = *(const bf16x8*)&Ac[row * 64 + (swz(row, ks * 64 + quad * 16) >> 1)];
    }
    if (pf) {
      stage_half(bB + k0n, K, &Bs[nb][0], tid);
      stage_half(bB + (size_t)128 * K + k0n, K, &Bs[nb][8192], tid);
    }
    __builtin_amdgcn_sched_barrier(0);
    __builtin_amdgcn_s_barrier();
    __builtin_amdgcn_s_setprio(1);
#pragma unroll
    for (int j = 0; j < 4; j++)
#pragma unroll
      for (int n = 0; n < 4; n++)
#pragma unroll
        for (int ks = 0; ks < 2; ks++)
          acc[4 + j][n] = __builtin_amdgcn_mfma_f32_16x16x32_bf16(ag[j][ks], bfr[n][ks], acc[4 + j][n], 0, 0, 0);
    __builtin_amdgcn_s_setprio(0);
    // tile-end: drain prefetch (in flight for ~2 phases) + fence buffer swap
    asm volatile("s_waitcnt vmcnt(0)" ::: "memory");
    __builtin_amdgcn_sched_barrier(0);
    __builtin_amdgcn_s_barrier();
  }

#pragma unroll
  for (int mt = 0; mt < 8; mt++) {
#pragma unroll
    for (int r = 0; r < 4; r++) {
      const int row = bm + wm + mt * 16 + quad * 4 + r;
      const size_t base = (size_t)row * N;
#pragma unroll
      for (int nt = 0; nt < 4; nt++) {
        const int col = bn + wn + nt * 16 + l16;
        float v = acc[mt][nt][r];
        if (EPI == 1)      v = Res[base + col] + v * Scale[col];
        else if (EPI == 2) { v = fmaxf(v, 0.f); v = v * v; }
        if constexpr (sizeof(OutT) == 2) C[base + col] = f2bf(v);
        else                             C[base + col] = v;
      }
    }
  }
}

// ---------------------------------------------------------------------------
// Row RMSNorm over 2048 (f32 in, bf16 out), one block (256 thr) per row.
// ---------------------------------------------------------------------------
__global__ __launch_bounds__(256)
void rmsnorm_k(const float* __restrict__ X, ushort_t* __restrict__ Y) {
  const int row = blockIdx.x, tid = threadIdx.x;
  const float* x = X + (size_t)row * 2048 + tid * 8;
  float v[8];
  *(float4*)&v[0] = *(const float4*)x;
  *(float4*)&v[4] = *(const float4*)(x + 4);
  float ss = 0.f;
#pragma unroll
  for (int i = 0; i < 8; i++) ss += v[i] * v[i];
  for (int o = 32; o; o >>= 1) ss += __shfl_xor(ss, o, 64);
  __shared__ float red[4];
  if ((tid & 63) == 0) red[tid >> 6] = ss;
  __syncthreads();
  const float tot = red[0] + red[1] + red[2] + red[3];
  const float sc = rsqrtf(tot * (1.0f / 2048.0f) + 1e-6f);
  u32x4 o4;
#pragma unroll
  for (int i = 0; i < 4; i++)
    o4[i] = (unsigned int)f2bf(v[2 * i] * sc) | ((unsigned int)f2bf(v[2 * i + 1] * sc) << 16);
  *(u32x4*)(Y + (size_t)row * 2048 + tid * 8) = o4;
}

// ---------------------------------------------------------------------------
// QK-norm + rotary. One wave per (token, head). Lane l owns pair (l, l+64).
// ---------------------------------------------------------------------------
__global__ __launch_bounds__(256)
void rotary_qk(ushort_t* __restrict__ qkv, float* __restrict__ kout,
               float* __restrict__ vout) {
  const int tid = threadIdx.x, wave = tid >> 6, lane = tid & 63;
  const int unit = blockIdx.x * 4 + wave;
  const int token = unit >> 4, h = unit & 15;
  const int t = token & 2047;
  ushort_t* qrow = qkv + (size_t)token * 6144 + h * 128;
  ushort_t* krow = qrow + 2048;
  const ushort_t* vrow = qrow + 4096;
  float q1 = bf2f(qrow[lane]), q2 = bf2f(qrow[lane + 64]);
  float k1 = bf2f(krow[lane]), k2 = bf2f(krow[lane + 64]);
  float sq = q1 * q1 + q2 * q2, sk = k1 * k1 + k2 * k2;
  for (int o = 32; o; o >>= 1) { sq += __shfl_xor(sq, o, 64); sk += __shfl_xor(sk, o, 64); }
  const float rq = rsqrtf(sq * (1.f / 128.f) + 1e-6f);
  const float rk = rsqrtf(sk * (1.f / 128.f) + 1e-6f);
  q1 *= rq; q2 *= rq; k1 *= rk; k2 *= rk;
  float c = 1.f, s = 0.f;
  if (lane < 32) {
    const float f = exp2f((float)lane * (-13.28771237954945f / 31.0f));
    const float th = (float)t * f;
    s = sinf(th); c = cosf(th);
  }
  const float qy1 = q1 * c + q2 * s, qy2 = -q1 * s + q2 * c;
  const float ky1 = k1 * c + k2 * s, ky2 = -k1 * s + k2 * c;
  const unsigned short qb1 = f2bf(qy1), qb2 = f2bf(qy2);
  const unsigned short kb1 = f2bf(ky1), kb2 = f2bf(ky2);
  qrow[lane] = qb1; qrow[lane + 64] = qb2;
  krow[lane] = kb1; krow[lane + 64] = kb2;
  float* ko = kout + (size_t)token * 2048 + h * 128;
  ko[lane] = bf2f(kb1); ko[lane + 64] = bf2f(kb2);
  float* vo = vout + (size_t)token * 2048 + h * 128;
  vo[lane] = bf2f(vrow[lane]); vo[lane + 64] = bf2f(vrow[lane + 64]);
}

// ---------------------------------------------------------------------------
// V transpose per (b,h): qkv v-section [T,128] -> Vt [128,T] (bf16).
// ---------------------------------------------------------------------------
__global__ __launch_bounds__(256)
void transpose_v(const ushort_t* __restrict__ qkv, ushort_t* __restrict__ vt) {
  __shared__ ushort_t tile[128][136];
  const int t16 = blockIdx.x, h = blockIdx.y, b = blockIdx.z;
  const int tid = threadIdx.x;
#pragma unroll
  for (int i = 0; i < 8; i++) {
    const int c = i * 256 + tid;
    const int row = c >> 4, cc = (c & 15) * 8;
    const size_t tok = (size_t)(b * 2048 + t16 * 128 + row);
    u32x4 d = *(const u32x4*)(qkv + tok * 6144 + 4096 + h * 128 + cc);
    *(u32x4*)&tile[row][cc] = d;
  }
  __syncthreads();
#pragma unroll
  for (int i = 0; i < 8; i++) {
    const int c = i * 256 + tid;
    const int hr = c >> 4, tc = (c & 15) * 8;
    u32x4 o;
#pragma unroll
    for (int j = 0; j < 4; j++) {
      const unsigned int lo = tile[tc + 2 * j][hr];
      const unsigned int hi = tile[tc + 2 * j + 1][hr];
      o[j] = lo | (hi << 16);
    }
    *(u32x4*)(vt + ((size_t)(b * 16 + h) * 128 + hr) * 2048 + t16 * 128 + tc) = o;
  }
}

// ---------------------------------------------------------------------------
// Causal flash attention (R4 structure: fixed-max softmax, prefetch dbuf,
// swizzles, remap). Unchanged this round.
// ---------------------------------------------------------------------------
__global__ __launch_bounds__(256)
void attn_k(const ushort_t* __restrict__ qkv, const ushort_t* __restrict__ vt,
            ushort_t* __restrict__ obuf) {
  __shared__ ushort_t kbuf[2][64 * 128];
  __shared__ ushort_t vbuf[2][128 * 64];
  __shared__ ushort_t pbuf[4][32 * 64];
  const int lin = blockIdx.x + (blockIdx.y << 4) + (blockIdx.z << 8);
  const int wid = ((lin & 7) << 7) + (lin >> 3);   // 1024 % 8 == 0 -> bijective
  const int qb = 15 - (wid & 15);
  const int h  = (wid >> 4) & 15;
  const int b  = wid >> 8;
  const int tid = threadIdx.x, wave = tid >> 6, lane = tid & 63;
  const int quad = lane >> 4, l16 = lane & 15;
  const float SCALE_L2E = 0.08838834764831845f * 1.44269504088896f;
  const float FML2 = 11.5f * 1.44269504088896f;

  const int nkt = qb * 2 + 2;
  const size_t kb0 = (size_t)(b * 2048) * 6144 + 2048 + h * 128;
  const size_t vt0 = (size_t)(b * 16 + h) * 128 * 2048;

  auto stage = [&](int bu, int kt) {
#pragma unroll
    for (int i = 0; i < 4; i++) {
      const int c = i * 256 + tid;
      const int kr = c >> 4, ck = c & 15;
      gld_lds16(qkv + kb0 + (size_t)(kt * 64 + kr) * 6144 + (ck ^ (kr & 7)) * 8,
                &kbuf[bu][c * 8]);
      const int hr = c >> 3, cv = c & 7;
      gld_lds16(vt + vt0 + (size_t)hr * 2048 + kt * 64 + (cv ^ (hr & 7)) * 8,
                &vbuf[bu][c * 8]);
    }
  };

  bf16x8 qf[2][4];
#pragma unroll
  for (int mt = 0; mt < 2; mt++)
#pragma unroll
    for (int ks = 0; ks < 4; ks++) {
      const int tok = b * 2048 + qb * 128 + wave * 32 + mt * 16 + l16;
      qf[mt][ks] = *(const bf16x8*)(qkv + (size_t)tok * 6144 + h * 128 + ks * 32 + quad * 8);
    }
  f32x4 O[2][8] = {};
  float lrow[2][4] = {};

  stage(0, 0);
  __syncthreads();

  for (int kt = 0; kt < nkt; kt++) {
    const int cur = kt & 1;
    if (kt + 1 < nkt) stage(cur ^ 1, kt + 1);
    __builtin_amdgcn_sched_barrier(0);

    f32x4 S[2][4] = {};
#pragma unroll
    for (int ks = 0; ks < 4; ks++) {
      bf16x8 kf[4];
#pragma unroll
      for (int nt = 0; nt < 4; nt++) {
        const int krow = nt * 16 + l16;
        kf[nt] = *(const bf16x8*)&kbuf[cur][krow * 128 + (swz(krow, ks * 64 + quad * 16) >> 1)];
      }
#pragma unroll
      for (int mt = 0; mt < 2; mt++)
#pragma unroll
        for (int nt = 0; nt < 4; nt++)
          S[mt][nt] = __builtin_amdgcn_mfma_f32_16x16x32_bf16(qf[mt][ks], kf[nt], S[mt][nt], 0, 0, 0);
    }
#pragma unroll
    for (int mt = 0; mt < 2; mt++) {
#pragma unroll
      for (int r = 0; r < 4; r++) {
        const int qr = qb * 128 + wave * 32 + mt * 16 + quad * 4 + r;
        const int prow = mt * 16 + quad * 4 + r;
        float rs = 0.f;
#pragma unroll
        for (int nt = 0; nt < 4; nt++) {
          const int kc = kt * 64 + nt * 16 + l16;
          float p = (kc > qr) ? 0.f : exp2f(fmaf(S[mt][nt][r], SCALE_L2E, -FML2));
          rs += p;
          pbuf[wave][prow * 64 + (swz(prow, (nt * 16 + l16) * 2) >> 1)] = f2bf(p);
        }
        lrow[mt][r] += rs;
      }
    }
#pragma unroll
    for (int ks = 0; ks < 2; ks++) {
      bf16x8 pa[2];
#pragma unroll
      for (int mt = 0; mt < 2; mt++) {
        const int parow = mt * 16 + l16;
        pa[mt] = *(const bf16x8*)&pbuf[wave][parow * 64 + (swz(parow, ks * 64 + quad * 16) >> 1)];
      }
#pragma unroll
      for (int nto = 0; nto < 8; nto++) {
        const int vrow = nto * 16 + l16;
        const bf16x8 vb = *(const bf16x8*)&vbuf[cur][vrow * 64 + (swz(vrow, ks * 64 + quad * 16) >> 1)];
#pragma unroll
        for (int mt = 0; mt < 2; mt++)
          O[mt][nto] = __builtin_amdgcn_mfma_f32_16x16x32_bf16(pa[mt], vb, O[mt][nto], 0, 0, 0);
      }
    }
    __syncthreads();
  }
#pragma unroll
  for (int mt = 0; mt < 2; mt++)
#pragma unroll
    for (int r = 0; r < 4; r++) {
      float ls = lrow[mt][r];
      for (int o = 1; o < 16; o <<= 1) ls += __shfl_xor(ls, o, 64);
      const float inv = 1.0f / ls;
      const int row = b * 2048 + qb * 128 + wave * 32 + mt * 16 + quad * 4 + r;
      const size_t base = (size_t)row * 2048 + h * 128;
#pragma unroll
      for (int nto = 0; nto < 8; nto++)
        obuf[base + nto * 16 + l16] = f2bf(O[mt][nto][r] * inv);
    }
}

// ---------------------------------------------------------------------------
extern "C" void kernel_launch(void* const* d_in, const int* in_sizes, int n_in,
                              void* d_out, int out_size, void* d_ws, size_t ws_size,
                              hipStream_t stream) {
  (void)in_sizes; (void)n_in; (void)out_size; (void)ws_size;
  const float* x       = (const float*)d_in[0];
  const float* qkv_w   = (const float*)d_in[1];
  const float* o_w     = (const float*)d_in[2];
  const float* o_scale = (const float*)d_in[3];
  const float* w1      = (const float*)d_in[4];
  const float* w2      = (const float*)d_in[5];
  const float* mscale  = (const float*)d_in[6];
  float* outx = (float*)d_out;                       // [4,2048,2048]   = 16777216
  float* outk = outx + (size_t)16777216;             // [4,2048,16,128] = 16777216
  float* outv = outk + (size_t)16777216;             // [4,2048,16,128] = 16777216

  char* ws = (char*)d_ws;
  ushort_t* qkv    = (ushort_t*)(ws + 0);            // 96 MB  [8192,6144] bf16
  ushort_t* vt     = (ushort_t*)(ws + 100663296);    // 32 MB  [4,16,128,2048] bf16
  ushort_t* xn     = (ushort_t*)(ws + 134217728);    // 32 MB  bf16 (xn / o / xn2 serial reuse)
  float*    x1     = (float*)   (ws + 167772160);    // 64 MB  f32
  ushort_t* qkv_wb = (ushort_t*)(ws + 234881024);    // 24 MB  bf16
  ushort_t* o_wb   = (ushort_t*)(ws + 260046848);    //  8 MB
  ushort_t* w1b    = (ushort_t*)(ws + 268435456);    // 32 MB
  ushort_t* w2b    = (ushort_t*)(ws + 301989888);    // 32 MB  (total 320 MB)
  ushort_t* hbuf   = (ushort_t*)(ws + 0);            // 128 MB overlays qkv+vt (dead after attn)

  cvt_bf16<<<12288, 256, 0, stream>>>(qkv_w, qkv_wb, 12582912);
  cvt_bf16<<<4096,  256, 0, stream>>>(o_w,   o_wb,   4194304);
  cvt_bf16<<<16384, 256, 0, stream>>>(w1,    w1b,    16777216);
  cvt_bf16<<<16384, 256, 0, stream>>>(w2,    w2b,    16777216);

  rmsnorm_k<<<8192, 256, 0, stream>>>(x, xn);
  gemm_bt256<0, ushort_t><<<dim3(24, 32), 512, 0, stream>>>(xn, qkv_wb, qkv, nullptr, nullptr, 8192, 6144, 2048);
  rotary_qk<<<32768, 256, 0, stream>>>(qkv, outk, outv);
  transpose_v<<<dim3(16, 16, 4), 256, 0, stream>>>(qkv, vt);
  attn_k<<<dim3(16, 16, 4), 256, 0, stream>>>(qkv, vt, xn /* o */);
  gemm_bt256<1, float><<<dim3(8, 32), 512, 0, stream>>>(xn /* o */, o_wb, x1, x, o_scale, 8192, 2048, 2048);
  rmsnorm_k<<<8192, 256, 0, stream>>>(x1, xn);
  gemm_bt256<2, ushort_t><<<dim3(32, 32), 512, 0, stream>>>(xn, w1b, hbuf, nullptr, nullptr, 8192, 8192, 2048);
  gemm_bt256<1, float><<<dim3(8, 32), 512, 0, stream>>>(hbuf, w2b, outx, x1, mscale, 8192, 2048, 8192);
}